// Round 24
// baseline (601.510 us; speedup 1.0000x reference)
//
#include <hip/hip_runtime.h>
#include <math.h>

#define NB 4
#define NSEQ 8192
#define DMODEL 512
#define NHEADS 8
#define DHEAD 64
#define NLM 256
#define LTOK 32
#define NBH 32
#define KCONV 33
#define CH3 8

typedef unsigned short bf16_t;
typedef __attribute__((ext_vector_type(8))) short bf16x8;
typedef __attribute__((ext_vector_type(4))) float f32x4;

__device__ __forceinline__ float bf2f(bf16_t u) {
  return __uint_as_float(((unsigned)u) << 16);
}
__device__ __forceinline__ bf16_t f2bf(float f) {
  unsigned u = __float_as_uint(f);
  return (bf16_t)((u + 0x7fffu + ((u >> 16) & 1u)) >> 16);  // RTNE
}
__device__ __forceinline__ void bfpair(unsigned u, float& lo, float& hi) {
  lo = __uint_as_float(u << 16);
  hi = __uint_as_float(u & 0xffff0000u);
}
// async global->LDS, 16B per lane; lds dest = wave-uniform base + lane*16
__device__ __forceinline__ void gload16(const bf16_t* g, bf16_t* l) {
  __builtin_amdgcn_global_load_lds(
      (const __attribute__((address_space(1))) unsigned int*)g,
      (__attribute__((address_space(3))) unsigned int*)l, 16, 0, 0);
}

// ---------------- LayerNorm ----------------
__global__ __launch_bounds__(256) void ln_kernel(const float* __restrict__ x,
    const float* __restrict__ gamma, const float* __restrict__ beta,
    bf16_t* __restrict__ xn) {
  int row = blockIdx.x * 4 + (threadIdx.x >> 6);
  int lane = threadIdx.x & 63;
  const float4* xr = reinterpret_cast<const float4*>(x + (size_t)row * DMODEL);
  float4 a0 = xr[lane];
  float4 a1 = xr[lane + 64];
  float s  = a0.x + a0.y + a0.z + a0.w + a1.x + a1.y + a1.z + a1.w;
  float s2 = a0.x*a0.x + a0.y*a0.y + a0.z*a0.z + a0.w*a0.w
           + a1.x*a1.x + a1.y*a1.y + a1.z*a1.z + a1.w*a1.w;
  #pragma unroll
  for (int off = 32; off; off >>= 1) {
    s  += __shfl_down(s, off);
    s2 += __shfl_down(s2, off);
  }
  s = __shfl(s, 0); s2 = __shfl(s2, 0);
  float mu = s * (1.0f / DMODEL);
  float var = s2 * (1.0f / DMODEL) - mu * mu;
  float rs = rsqrtf(var + 1e-5f);
  const float4* g4 = reinterpret_cast<const float4*>(gamma);
  const float4* b4 = reinterpret_cast<const float4*>(beta);
  float4 g0 = g4[lane], g1 = g4[lane + 64];
  float4 bb0 = b4[lane], bb1 = b4[lane + 64];
  ushort4 o0, o1;
  o0.x = f2bf((a0.x - mu) * rs * g0.x + bb0.x);
  o0.y = f2bf((a0.y - mu) * rs * g0.y + bb0.y);
  o0.z = f2bf((a0.z - mu) * rs * g0.z + bb0.z);
  o0.w = f2bf((a0.w - mu) * rs * g0.w + bb0.w);
  o1.x = f2bf((a1.x - mu) * rs * g1.x + bb1.x);
  o1.y = f2bf((a1.y - mu) * rs * g1.y + bb1.y);
  o1.z = f2bf((a1.z - mu) * rs * g1.z + bb1.z);
  o1.w = f2bf((a1.w - mu) * rs * g1.w + bb1.w);
  ushort4* o = reinterpret_cast<ushort4*>(xn + (size_t)row * DMODEL);
  o[lane] = o0; o[lane + 64] = o1;
}

// -------- merged transpose-cast of both weights (q cols pre-scaled); scal[0]=1.0 --------
__global__ void castT2_kernel(const float* __restrict__ wqkv, const float* __restrict__ wout,
                              bf16_t* __restrict__ wqkvT, bf16_t* __restrict__ woutT,
                              unsigned int* __restrict__ scal) {
  int idx = blockIdx.x * 256 + threadIdx.x;  // 786432 + 262144
  if (idx == 0) scal[0] = 0x3f800000u;  // col = row-sum max of softmax rows == 1.0
  if (idx == 1) scal[1] = 0u;
  if (idx < 786432) {
    int k = idx & 511, c = idx >> 9;
    float v = wqkv[(size_t)k * 1536 + c];
    if (c < 512) v *= 0.125f;  // dh^-0.5 folded into q weights
    wqkvT[idx] = f2bf(v);
  } else {
    int i = idx - 786432;
    int k = i & 511, c = i >> 9;
    woutT[i] = f2bf(wout[(size_t)k * 512 + c]);
  }
}

// ---- MFMA QKV GEMM: gload_lds BK=64 split buffers; XCD-swizzled 1-D grid ----
// bid&7 = XCD slot; each XCD owns 32 consecutive rowB panels, iterating all 12
// colB per panel -> A panel fetched ~once per XCD (L2-resident with B).
__global__ __launch_bounds__(256) void gemm_qkv_mfma(const bf16_t* __restrict__ A,
    const bf16_t* __restrict__ Bt, bf16_t* __restrict__ q, bf16_t* __restrict__ k,
    bf16_t* __restrict__ v) {
  __shared__ __align__(16) bf16_t As0[128 * 32];
  __shared__ __align__(16) bf16_t As1[128 * 32];
  __shared__ __align__(16) bf16_t Bs0[128 * 32];
  __shared__ __align__(16) bf16_t Bs1[128 * 32];
  int bid = blockIdx.x;
  int xcd = bid & 7;
  int idx = bid >> 3;                 // 0..383
  int rowT = xcd * 32 + idx / 12;     // 0..255
  int colT = idx % 12;                // 0..11
  int rowB = rowT * 128, colB = colT * 128;
  int tid = threadIdx.x;
  int wave = tid >> 6, lane = tid & 63;
  int wr = (wave >> 1) * 64, wc = (wave & 1) * 64;
  int lrow = lane & 15, g = lane >> 4;
  f32x4 acc[4][4] = {};
  for (int k0 = 0; k0 < DMODEL; k0 += 64) {
    #pragma unroll
    for (int c = 0; c < 2; ++c) {
      int eb = wave * 1024 + c * 512;       // wave-uniform element base
      int e = eb + lane * 8;
      int r = e >> 5, cc = e & 31;
      gload16(A + (size_t)(rowB + r) * DMODEL + k0 + cc, &As0[eb]);
      gload16(A + (size_t)(rowB + r) * DMODEL + k0 + 32 + cc, &As1[eb]);
      gload16(Bt + (size_t)(colB + r) * DMODEL + k0 + cc, &Bs0[eb]);
      gload16(Bt + (size_t)(colB + r) * DMODEL + k0 + 32 + cc, &Bs1[eb]);
    }
    __syncthreads();
    #pragma unroll
    for (int ks = 0; ks < 2; ++ks) {
      const bf16_t* Ab2 = ks ? As1 : As0;
      const bf16_t* Bb2 = ks ? Bs1 : Bs0;
      bf16x8 af[4], bf[4];
      #pragma unroll
      for (int m = 0; m < 4; ++m)
        af[m] = *reinterpret_cast<const bf16x8*>(&Ab2[(wr + m * 16 + lrow) * 32 + g * 8]);
      #pragma unroll
      for (int n = 0; n < 4; ++n)
        bf[n] = *reinterpret_cast<const bf16x8*>(&Bb2[(wc + n * 16 + lrow) * 32 + g * 8]);
      #pragma unroll
      for (int m = 0; m < 4; ++m)
        #pragma unroll
        for (int n = 0; n < 4; ++n)
          acc[m][n] = __builtin_amdgcn_mfma_f32_16x16x32_bf16(af[m], bf[n], acc[m][n], 0, 0, 0);
    }
    __syncthreads();
  }
  #pragma unroll
  for (int m = 0; m < 4; ++m) {
    #pragma unroll
    for (int n = 0; n < 4; ++n) {
      int col = colB + wc + n * 16 + lrow;
      int which = col >> 9, hc = col & 511, h = hc >> 6, d = hc & 63;
      bf16_t* dst = (which == 0) ? q : (which == 1 ? k : v);
      #pragma unroll
      for (int r = 0; r < 4; ++r) {
        int row = rowB + wr + m * 16 + g * 4 + r;
        int b = row >> 13, nn = row & 8191;
        dst[((size_t)(b * NHEADS + h) * NSEQ + nn) * DHEAD + d] = f2bf(acc[m][n][r]);
      }
    }
  }
}

// ---------------- MFMA out GEMM: gload_lds staging, swapped float4 epilogue ----------------
__global__ __launch_bounds__(256) void gemm_out_mfma(const bf16_t* __restrict__ A,
    const bf16_t* __restrict__ Bt, const float* __restrict__ bo,
    const float* __restrict__ x, float* __restrict__ y) {
  __shared__ __align__(16) bf16_t As[128 * 32];
  __shared__ __align__(16) bf16_t Bs[128 * 32];
  int rowB = blockIdx.x * 128, colB = blockIdx.y * 128;
  int tid = threadIdx.x;
  int wave = tid >> 6, lane = tid & 63;
  int wr = (wave >> 1) * 64, wc = (wave & 1) * 64;
  int lrow = lane & 15, g = lane >> 4;
  f32x4 acc[4][4] = {};  // [n][m]
  for (int k0 = 0; k0 < DMODEL; k0 += 32) {
    #pragma unroll
    for (int c = 0; c < 2; ++c) {
      int eb = wave * 1024 + c * 512;
      int e = eb + lane * 8;
      int r = e >> 5, cc = e & 31;
      gload16(A + (size_t)(rowB + r) * DMODEL + k0 + cc, &As[eb]);
      gload16(Bt + (size_t)(colB + r) * DMODEL + k0 + cc, &Bs[eb]);
    }
    __syncthreads();
    bf16x8 af[4], bf[4];
    #pragma unroll
    for (int m = 0; m < 4; ++m)
      af[m] = *reinterpret_cast<const bf16x8*>(&As[(wr + m * 16 + lrow) * 32 + g * 8]);
    #pragma unroll
    for (int n = 0; n < 4; ++n)
      bf[n] = *reinterpret_cast<const bf16x8*>(&Bs[(wc + n * 16 + lrow) * 32 + g * 8]);
    #pragma unroll
    for (int n = 0; n < 4; ++n)
      #pragma unroll
      for (int m = 0; m < 4; ++m)
        acc[n][m] = __builtin_amdgcn_mfma_f32_16x16x32_bf16(bf[n], af[m], acc[n][m], 0, 0, 0);
    __syncthreads();
  }
  #pragma unroll
  for (int n = 0; n < 4; ++n) {
    int c0 = colB + wc + n * 16 + g * 4;
    float4 b4 = *reinterpret_cast<const float4*>(&bo[c0]);
    #pragma unroll
    for (int m = 0; m < 4; ++m) {
      int row = rowB + wr + m * 16 + lrow;
      size_t off = (size_t)row * DMODEL + c0;
      float4 xv = *reinterpret_cast<const float4*>(&x[off]);
      float4 o;
      o.x = xv.x + b4.x + acc[n][m][0];
      o.y = xv.y + b4.y + acc[n][m][1];
      o.z = xv.z + b4.z + acc[n][m][2];
      o.w = xv.w + b4.w + acc[n][m][3];
      *reinterpret_cast<float4*>(&y[off]) = o;
    }
  }
}

// -------- conflict-free 64x64 tiled transpose: src [bh][R][64] -> dst [bh][64][R] --------
__global__ __launch_bounds__(256) void transpose64_kernel(const bf16_t* __restrict__ src,
    bf16_t* __restrict__ dst, int R) {
  __shared__ __align__(16) bf16_t T[64 * 64];
  int r0 = blockIdx.x * 64, bh = blockIdx.y;
  int tid = threadIdx.x;
  int jj = tid >> 2, part = tid & 3;
  const uint4* sr = reinterpret_cast<const uint4*>(
      src + ((size_t)bh * R + r0 + jj) * 64 + part * 16);
  uint4 a0 = sr[0], a1 = sr[1];
  int xr = (jj >> 3) & 7;
  int pg0 = (part * 2) ^ xr, pg1 = (part * 2 + 1) ^ xr;
  *reinterpret_cast<uint4*>(&T[jj * 64 + pg0 * 8]) = a0;
  *reinterpret_cast<uint4*>(&T[jj * 64 + pg1 * 8]) = a1;
  __syncthreads();
  int d = tid >> 2;
  unsigned ow[8];
  #pragma unroll
  for (int ee = 0; ee < 8; ++ee) {
    int n1 = part * 16 + ee * 2, n2 = n1 + 1;
    unsigned lo = T[n1 * 64 + (((d >> 3) ^ ((n1 >> 3) & 7)) * 8) + (d & 7)];
    unsigned hi = T[n2 * 64 + (((d >> 3) ^ ((n2 >> 3) & 7)) * 8) + (d & 7)];
    ow[ee] = lo | (hi << 16);
  }
  uint4* ot = reinterpret_cast<uint4*>(dst + ((size_t)bh * 64 + d) * R + r0 + part * 16);
  ot[0] = make_uint4(ow[0], ow[1], ow[2], ow[3]);
  ot[1] = make_uint4(ow[4], ow[5], ow[6], ow[7]);
}

// ---------------- landmark pooling: fp32 (attn2) + bf16 (flash) ----------------
__global__ void pool_kernel(const bf16_t* __restrict__ q, const bf16_t* __restrict__ k,
                            float* __restrict__ ql, float* __restrict__ kl,
                            bf16_t* __restrict__ qlb, bf16_t* __restrict__ klb) {
  int idx = blockIdx.x * 256 + threadIdx.x;
  const int half = NBH * NLM * DHEAD;
  const bf16_t* src = (idx < half) ? q : k;
  float* dst = (idx < half) ? ql : kl;
  bf16_t* dstb = (idx < half) ? qlb : klb;
  int i = (idx < half) ? idx : idx - half;
  int d = i & 63, m = (i >> 6) & 255, bh = i >> 14;
  const bf16_t* p = src + ((size_t)bh * NSEQ + m * LTOK) * DHEAD + d;
  float sum = 0.f;
  #pragma unroll
  for (int t = 0; t < LTOK; ++t) sum += bf2f(p[(size_t)t * DHEAD]);
  float r = sum * (1.0f / LTOK);
  dst[i] = r;
  dstb[i] = f2bf(r);
}

// ---------------- attn2 = softmax(q_l @ k_l^T) fp32 ----------------
__global__ __launch_bounds__(256) void attn2_kernel(const float* __restrict__ ql,
    const float* __restrict__ kl, float* __restrict__ a2) {
  __shared__ float qs[64];
  __shared__ float red[256];
  int bh = blockIdx.y, i = blockIdx.x, t = threadIdx.x;
  if (t < 64) qs[t] = ql[((size_t)bh * NLM + i) * DHEAD + t];
  __syncthreads();
  const float* kr = kl + ((size_t)bh * NLM + t) * DHEAD;
  float s = 0.f;
  #pragma unroll
  for (int d = 0; d < 64; ++d) s += qs[d] * kr[d];
  red[t] = s; __syncthreads();
  for (int off = 128; off; off >>= 1) { if (t < off) red[t] = fmaxf(red[t], red[t + off]); __syncthreads(); }
  float mx = red[0]; __syncthreads();
  float p = expf(s - mx);
  red[t] = p; __syncthreads();
  for (int off = 128; off; off >>= 1) { if (t < off) red[t] += red[t + off]; __syncthreads(); }
  a2[((size_t)bh * NLM + i) * NLM + t] = p / red[0];
}

// column-sum max only (row-sums of softmax are exactly 1 -> scal[0] preset)
__global__ void colrow_kernel(const float* __restrict__ a2, unsigned int* __restrict__ scal) {
  int bh = blockIdx.x;
  int t = threadIdx.x;
  const float* Ab = a2 + (size_t)bh * NLM * NLM;
  float sum = 0.f;
  for (int i2 = 0; i2 < NLM; ++i2) sum += fabsf(Ab[(size_t)i2 * NLM + t]);
  __shared__ float red[256];
  red[t] = sum; __syncthreads();
  for (int off = 128; off; off >>= 1) { if (t < off) red[t] = fmaxf(red[t], red[t + off]); __syncthreads(); }
  if (t == 0) atomicMax(&scal[1], __float_as_uint(red[0]));
}

// z0 = a^T/(col*row) in bf16, plus a2 cast to bf16
__global__ void zinit_kernel(const float* __restrict__ a2, const unsigned int* __restrict__ scal,
                             bf16_t* __restrict__ zb, bf16_t* __restrict__ a2b) {
  int idx = blockIdx.x * 256 + threadIdx.x;
  float inv = 1.0f / (__uint_as_float(scal[0]) * __uint_as_float(scal[1]));
  int j = idx & 255, i = (idx >> 8) & 255, bh = idx >> 16;
  zb[idx] = f2bf(a2[((size_t)bh * NLM + j) * NLM + i] * inv);
  a2b[idx] = f2bf(a2[idx]);
}

// ---------------- batched 256x256 matmul, bf16 in / bf16 out (2-stage, swapped epilogue) ----------------
__global__ __launch_bounds__(256) void matmul256_b2b(bf16_t* __restrict__ C,
    const bf16_t* __restrict__ A, const bf16_t* __restrict__ Bm, float s, float alpha) {
  __shared__ __align__(16) bf16_t Ah[64][72];
  __shared__ __align__(16) bf16_t Bh[64][72];
  int bh = blockIdx.y;
  const bf16_t* Ab = A + (size_t)bh * NLM * NLM;
  const bf16_t* Bb = Bm + (size_t)bh * NLM * NLM;
  bf16_t* Cb = C + (size_t)bh * NLM * NLM;
  int rowB = (blockIdx.x >> 2) * 64, colB = (blockIdx.x & 3) * 64;
  int tid = threadIdx.x, w = tid >> 6, lane = tid & 63, tx = lane & 15, g = lane >> 4;
  int jj = tid >> 2, part = tid & 3;
  f32x4 acc[4] = {};
  for (int k0 = 0; k0 < NLM; k0 += 64) {
    {
      const uint4* ar = reinterpret_cast<const uint4*>(
          Ab + (size_t)(rowB + jj) * NLM + k0 + part * 16);
      *reinterpret_cast<uint4*>(&Ah[jj][part * 16]) = ar[0];
      *reinterpret_cast<uint4*>(&Ah[jj][part * 16 + 8]) = ar[1];
      const uint4* br = reinterpret_cast<const uint4*>(
          Bb + (size_t)(k0 + jj) * NLM + colB + part * 16);
      uint4 b0 = br[0], b1 = br[1];
      int d0 = part * 16;
      Bh[d0+ 0][jj] = (bf16_t)(b0.x & 0xffffu); Bh[d0+ 1][jj] = (bf16_t)(b0.x >> 16);
      Bh[d0+ 2][jj] = (bf16_t)(b0.y & 0xffffu); Bh[d0+ 3][jj] = (bf16_t)(b0.y >> 16);
      Bh[d0+ 4][jj] = (bf16_t)(b0.z & 0xffffu); Bh[d0+ 5][jj] = (bf16_t)(b0.z >> 16);
      Bh[d0+ 6][jj] = (bf16_t)(b0.w & 0xffffu); Bh[d0+ 7][jj] = (bf16_t)(b0.w >> 16);
      Bh[d0+ 8][jj] = (bf16_t)(b1.x & 0xffffu); Bh[d0+ 9][jj] = (bf16_t)(b1.x >> 16);
      Bh[d0+10][jj] = (bf16_t)(b1.y & 0xffffu); Bh[d0+11][jj] = (bf16_t)(b1.y >> 16);
      Bh[d0+12][jj] = (bf16_t)(b1.z & 0xffffu); Bh[d0+13][jj] = (bf16_t)(b1.z >> 16);
      Bh[d0+14][jj] = (bf16_t)(b1.w & 0xffffu); Bh[d0+15][jj] = (bf16_t)(b1.w >> 16);
    }
    __syncthreads();
    #pragma unroll
    for (int ks = 0; ks < 2; ++ks) {
      bf16x8 ah = *reinterpret_cast<const bf16x8*>(&Ah[w * 16 + tx][g * 8 + 32 * ks]);
      #pragma unroll
      for (int tn = 0; tn < 4; ++tn) {
        bf16x8 bhf = *reinterpret_cast<const bf16x8*>(&Bh[tn * 16 + tx][g * 8 + 32 * ks]);
        acc[tn] = __builtin_amdgcn_mfma_f32_16x16x32_bf16(bhf, ah, acc[tn], 0, 0, 0);
      }
    }
    __syncthreads();
  }
  int rr = rowB + w * 16 + tx;
  #pragma unroll
  for (int tn = 0; tn < 4; ++tn) {
    int c0 = colB + tn * 16 + g * 4;
    size_t off = (size_t)rr * NLM + c0;
    float a0 = 0.f, a1 = 0.f, a2v = 0.f, a3 = 0.f;
    if (s != 0.0f) {
      ushort4 av = *reinterpret_cast<const ushort4*>(&Ab[off]);
      a0 = bf2f(av.x); a1 = bf2f(av.y); a2v = bf2f(av.z); a3 = bf2f(av.w);
    }
    ushort4 o;
    o.x = f2bf(alpha * (s * a0 - acc[tn][0]));
    o.y = f2bf(alpha * (s * a1 - acc[tn][1]));
    o.z = f2bf(alpha * (s * a2v - acc[tn][2]));
    o.w = f2bf(alpha * (s * a3 - acc[tn][3]));
    *reinterpret_cast<ushort4*>(&Cb[off]) = o;
  }
}

// ---- dual-product variant: blockIdx.z selects (C0,A0) or (C1,A1), shared B ----
__global__ __launch_bounds__(256) void matmul256_b2b2(
    bf16_t* __restrict__ C0, const bf16_t* __restrict__ A0,
    bf16_t* __restrict__ C1, const bf16_t* __restrict__ A1,
    const bf16_t* __restrict__ Bm, float s, float alpha) {
  __shared__ __align__(16) bf16_t Ah[64][72];
  __shared__ __align__(16) bf16_t Bh[64][72];
  int bh = blockIdx.y;
  const bf16_t* A = (blockIdx.z == 0) ? A0 : A1;
  bf16_t* C = (blockIdx.z == 0) ? C0 : C1;
  const bf16_t* Ab = A + (size_t)bh * NLM * NLM;
  const bf16_t* Bb = Bm + (size_t)bh * NLM * NLM;
  bf16_t* Cb = C + (size_t)bh * NLM * NLM;
  int rowB = (blockIdx.x >> 2) * 64, colB = (blockIdx.x & 3) * 64;
  int tid = threadIdx.x, w = tid >> 6, lane = tid & 63, tx = lane & 15, g = lane >> 4;
  int jj = tid >> 2, part = tid & 3;
  f32x4 acc[4] = {};
  for (int k0 = 0; k0 < NLM; k0 += 64) {
    {
      const uint4* ar = reinterpret_cast<const uint4*>(
          Ab + (size_t)(rowB + jj) * NLM + k0 + part * 16);
      *reinterpret_cast<uint4*>(&Ah[jj][part * 16]) = ar[0];
      *reinterpret_cast<uint4*>(&Ah[jj][part * 16 + 8]) = ar[1];
      const uint4* br = reinterpret_cast<const uint4*>(
          Bb + (size_t)(k0 + jj) * NLM + colB + part * 16);
      uint4 b0 = br[0], b1 = br[1];
      int d0 = part * 16;
      Bh[d0+ 0][jj] = (bf16_t)(b0.x & 0xffffu); Bh[d0+ 1][jj] = (bf16_t)(b0.x >> 16);
      Bh[d0+ 2][jj] = (bf16_t)(b0.y & 0xffffu); Bh[d0+ 3][jj] = (bf16_t)(b0.y >> 16);
      Bh[d0+ 4][jj] = (bf16_t)(b0.z & 0xffffu); Bh[d0+ 5][jj] = (bf16_t)(b0.z >> 16);
      Bh[d0+ 6][jj] = (bf16_t)(b0.w & 0xffffu); Bh[d0+ 7][jj] = (bf16_t)(b0.w >> 16);
      Bh[d0+ 8][jj] = (bf16_t)(b1.x & 0xffffu); Bh[d0+ 9][jj] = (bf16_t)(b1.x >> 16);
      Bh[d0+10][jj] = (bf16_t)(b1.y & 0xffffu); Bh[d0+11][jj] = (bf16_t)(b1.y >> 16);
      Bh[d0+12][jj] = (bf16_t)(b1.z & 0xffffu); Bh[d0+13][jj] = (bf16_t)(b1.z >> 16);
      Bh[d0+14][jj] = (bf16_t)(b1.w & 0xffffu); Bh[d0+15][jj] = (bf16_t)(b1.w >> 16);
    }
    __syncthreads();
    #pragma unroll
    for (int ks = 0; ks < 2; ++ks) {
      bf16x8 ah = *reinterpret_cast<const bf16x8*>(&Ah[w * 16 + tx][g * 8 + 32 * ks]);
      #pragma unroll
      for (int tn = 0; tn < 4; ++tn) {
        bf16x8 bhf = *reinterpret_cast<const bf16x8*>(&Bh[tn * 16 + tx][g * 8 + 32 * ks]);
        acc[tn] = __builtin_amdgcn_mfma_f32_16x16x32_bf16(bhf, ah, acc[tn], 0, 0, 0);
      }
    }
    __syncthreads();
  }
  int rr = rowB + w * 16 + tx;
  #pragma unroll
  for (int tn = 0; tn < 4; ++tn) {
    int c0 = colB + tn * 16 + g * 4;
    size_t off = (size_t)rr * NLM + c0;
    ushort4 av = *reinterpret_cast<const ushort4*>(&Ab[off]);
    float a0 = bf2f(av.x), a1 = bf2f(av.y), a2v = bf2f(av.z), a3 = bf2f(av.w);
    ushort4 o;
    o.x = f2bf(alpha * (s * a0 - acc[tn][0]));
    o.y = f2bf(alpha * (s * a1 - acc[tn][1]));
    o.z = f2bf(alpha * (s * a2v - acc[tn][2]));
    o.w = f2bf(alpha * (s * a3 - acc[tn][3]));
    *reinterpret_cast<ushort4*>(&Cb[off]) = o;
  }
}

// ---------------- batched 256x256 matmul, bf16 in / fp32 out (2-stage, swapped epilogue) ----------------
__global__ __launch_bounds__(256) void matmul256_b2f(float* __restrict__ C,
    const bf16_t* __restrict__ A, const bf16_t* __restrict__ Bm, float s, float alpha) {
  __shared__ __align__(16) bf16_t Ah[64][72];
  __shared__ __align__(16) bf16_t Bh[64][72];
  int bh = blockIdx.y;
  const bf16_t* Ab = A + (size_t)bh * NLM * NLM;
  const bf16_t* Bb = Bm + (size_t)bh * NLM * NLM;
  float* Cb = C + (size_t)bh * NLM * NLM;
  int rowB = (blockIdx.x >> 2) * 64, colB = (blockIdx.x & 3) * 64;
  int tid = threadIdx.x, w = tid >> 6, lane = tid & 63, tx = lane & 15, g = lane >> 4;
  int jj = tid >> 2, part = tid & 3;
  f32x4 acc[4] = {};
  for (int k0 = 0; k0 < NLM; k0 += 64) {
    {
      const uint4* ar = reinterpret_cast<const uint4*>(
          Ab + (size_t)(rowB + jj) * NLM + k0 + part * 16);
      *reinterpret_cast<uint4*>(&Ah[jj][part * 16]) = ar[0];
      *reinterpret_cast<uint4*>(&Ah[jj][part * 16 + 8]) = ar[1];
      const uint4* br = reinterpret_cast<const uint4*>(
          Bb + (size_t)(k0 + jj) * NLM + colB + part * 16);
      uint4 b0 = br[0], b1 = br[1];
      int d0 = part * 16;
      Bh[d0+ 0][jj] = (bf16_t)(b0.x & 0xffffu); Bh[d0+ 1][jj] = (bf16_t)(b0.x >> 16);
      Bh[d0+ 2][jj] = (bf16_t)(b0.y & 0xffffu); Bh[d0+ 3][jj] = (bf16_t)(b0.y >> 16);
      Bh[d0+ 4][jj] = (bf16_t)(b0.z & 0xffffu); Bh[d0+ 5][jj] = (bf16_t)(b0.z >> 16);
      Bh[d0+ 6][jj] = (bf16_t)(b0.w & 0xffffu); Bh[d0+ 7][jj] = (bf16_t)(b0.w >> 16);
      Bh[d0+ 8][jj] = (bf16_t)(b1.x & 0xffffu); Bh[d0+ 9][jj] = (bf16_t)(b1.x >> 16);
      Bh[d0+10][jj] = (bf16_t)(b1.y & 0xffffu); Bh[d0+11][jj] = (bf16_t)(b1.y >> 16);
      Bh[d0+12][jj] = (bf16_t)(b1.z & 0xffffu); Bh[d0+13][jj] = (bf16_t)(b1.z >> 16);
      Bh[d0+14][jj] = (bf16_t)(b1.w & 0xffffu); Bh[d0+15][jj] = (bf16_t)(b1.w >> 16);
    }
    __syncthreads();
    #pragma unroll
    for (int ks = 0; ks < 2; ++ks) {
      bf16x8 ah = *reinterpret_cast<const bf16x8*>(&Ah[w * 16 + tx][g * 8 + 32 * ks]);
      #pragma unroll
      for (int tn = 0; tn < 4; ++tn) {
        bf16x8 bhf = *reinterpret_cast<const bf16x8*>(&Bh[tn * 16 + tx][g * 8 + 32 * ks]);
        acc[tn] = __builtin_amdgcn_mfma_f32_16x16x32_bf16(bhf, ah, acc[tn], 0, 0, 0);
      }
    }
    __syncthreads();
  }
  int rr = rowB + w * 16 + tx;
  #pragma unroll
  for (int tn = 0; tn < 4; ++tn) {
    int c0 = colB + tn * 16 + g * 4;
    size_t off = (size_t)rr * NLM + c0;
    float a0 = 0.f, a1 = 0.f, a2v = 0.f, a3 = 0.f;
    if (s != 0.0f) {
      ushort4 av = *reinterpret_cast<const ushort4*>(&Ab[off]);
      a0 = bf2f(av.x); a1 = bf2f(av.y); a2v = bf2f(av.z); a3 = bf2f(av.w);
    }
    float4 o;
    o.x = alpha * (s * a0 - acc[tn][0]);
    o.y = alpha * (s * a1 - acc[tn][1]);
    o.z = alpha * (s * a2v - acc[tn][2]);
    o.w = alpha * (s * a3 - acc[tn][3]);
    *reinterpret_cast<float4*>(&Cb[off]) = o;
  }
}

// ------- MFMA flash attn3@v: gload_lds split pitch-32 staging, swapped PV epilogue -------
__global__ __launch_bounds__(256) void attn3v_mfma(const bf16_t* __restrict__ qlb,
    const bf16_t* __restrict__ k, const bf16_t* __restrict__ vT,
    float* __restrict__ Wpart, float* __restrict__ mlpart) {
  __shared__ __align__(16) bf16_t Qs0[2048], Qs1[2048];
  __shared__ __align__(16) bf16_t Ks0[2048], Ks1[2048];
  __shared__ __align__(16) bf16_t Vs0[2048], Vs1[2048];
  __shared__ __align__(16) bf16_t Ps[64][72];
  int chunk = blockIdx.x, lmt = blockIdx.y, bh = blockIdx.z;
  int tid = threadIdx.x;
  int wave = tid >> 6, lane = tid & 63;
  int w = wave, tx = lane & 15, g = lane >> 4;
  int lm0 = lmt * 64;
  const bf16_t* kb = k + (size_t)bh * NSEQ * DHEAD;
  const bf16_t* vtb = vT + (size_t)bh * DHEAD * NSEQ;
  int eb = wave * 512;
  int e = eb + lane * 8;
  int sr = e >> 5, sc = e & 31;
  {
    const bf16_t* qrow = qlb + ((size_t)bh * NLM + lm0 + sr) * DHEAD;
    gload16(qrow + sc, &Qs0[eb]);
    gload16(qrow + 32 + sc, &Qs1[eb]);
  }
  f32x4 oacc[4] = {};
  float lreg[4] = {0.f, 0.f, 0.f, 0.f};
  __syncthreads();
  bf16x8 aq0 = *reinterpret_cast<const bf16x8*>(&Qs0[(w * 16 + tx) * 32 + g * 8]);
  bf16x8 aq1 = *reinterpret_cast<const bf16x8*>(&Qs1[(w * 16 + tx) * 32 + g * 8]);
  for (int it = 0; it < NSEQ / (CH3 * 64); ++it) {
    int n0 = chunk * (NSEQ / CH3) + it * 64;
    {
      const bf16_t* krow = kb + (size_t)(n0 + sr) * DHEAD;
      gload16(krow + sc, &Ks0[eb]);
      gload16(krow + 32 + sc, &Ks1[eb]);
      const bf16_t* vrow = vtb + (size_t)sr * NSEQ + n0;
      gload16(vrow + sc, &Vs0[eb]);
      gload16(vrow + 32 + sc, &Vs1[eb]);
    }
    __syncthreads();
    f32x4 sacc[4] = {};
    #pragma unroll
    for (int tn = 0; tn < 4; ++tn) {
      bf16x8 bk0 = *reinterpret_cast<const bf16x8*>(&Ks0[(tn * 16 + tx) * 32 + g * 8]);
      bf16x8 bk1 = *reinterpret_cast<const bf16x8*>(&Ks1[(tn * 16 + tx) * 32 + g * 8]);
      sacc[tn] = __builtin_amdgcn_mfma_f32_16x16x32_bf16(aq0, bk0, sacc[tn], 0, 0, 0);
      sacc[tn] = __builtin_amdgcn_mfma_f32_16x16x32_bf16(aq1, bk1, sacc[tn], 0, 0, 0);
    }
    #pragma unroll
    for (int r = 0; r < 4; ++r) {
      float p0 = __expf(sacc[0][r]);
      float p1 = __expf(sacc[1][r]);
      float p2 = __expf(sacc[2][r]);
      float p3 = __expf(sacc[3][r]);
      float ts = p0 + p1 + p2 + p3;
      #pragma unroll
      for (int off = 1; off < 16; off <<= 1) ts += __shfl_xor(ts, off);
      lreg[r] += ts;
      int prow = w * 16 + g * 4 + r;
      Ps[prow][tx]      = f2bf(p0);
      Ps[prow][tx + 16] = f2bf(p1);
      Ps[prow][tx + 32] = f2bf(p2);
      Ps[prow][tx + 48] = f2bf(p3);
    }
    __syncthreads();
    bf16x8 ap0 = *reinterpret_cast<const bf16x8*>(&Ps[w * 16 + tx][g * 8]);
    bf16x8 ap1 = *reinterpret_cast<const bf16x8*>(&Ps[w * 16 + tx][g * 8 + 32]);
    #pragma unroll
    for (int td = 0; td < 4; ++td) {
      bf16x8 bv0 = *reinterpret_cast<const bf16x8*>(&Vs0[(td * 16 + tx) * 32 + g * 8]);
      bf16x8 bv1 = *reinterpret_cast<const bf16x8*>(&Vs1[(td * 16 + tx) * 32 + g * 8]);
      oacc[td] = __builtin_amdgcn_mfma_f32_16x16x32_bf16(bv0, ap0, oacc[td], 0, 0, 0);
      oacc[td] = __builtin_amdgcn_mfma_f32_16x16x32_bf16(bv1, ap1, oacc[td], 0, 0, 0);
    }
    __syncthreads();
  }
  size_t ob = ((size_t)(chunk * NBH + bh) * NLM + lm0 + w * 16 + tx);
  #pragma unroll
  for (int td = 0; td < 4; ++td) {
    float4 w4 = make_float4(oacc[td][0], oacc[td][1], oacc[td][2], oacc[td][3]);
    *reinterpret_cast<float4*>(&Wpart[ob * DHEAD + td * 16 + g * 4]) = w4;
  }
  if (tx == 0) {
    #pragma unroll
    for (int r = 0; r < 4; ++r) {
      size_t obr = ((size_t)(chunk * NBH + bh) * NLM + lm0 + w * 16 + g * 4 + r);
      mlpart[obr] = lreg[r];
    }
  }
}

// combine CH3 chunks (no-max softmax: plain sums)
__global__ void attn3v_combine(const float* __restrict__ Wpart,
    const float* __restrict__ mlpart, float* __restrict__ Wm) {
  int idx = blockIdx.x * 256 + threadIdx.x;
  int d = idx & 63;
  int s0 = idx >> 6;
  const int CHS = NBH * NLM;
  float L = 0.f, wv = 0.f;
  #pragma unroll
  for (int c = 0; c < CH3; ++c) {
    L += mlpart[(size_t)c * CHS + s0];
    wv += Wpart[((size_t)c * CHS + s0) * DHEAD + d];
  }
  Wm[idx] = wv / L;
}

// ---------------- U = Z @ W, bf16 out ----------------
__global__ void zw_kernel(const float* __restrict__ z, const float* __restrict__ W,
                          bf16_t* __restrict__ Ub) {
  int idx = blockIdx.x * 256 + threadIdx.x;
  int d = idx & 63, i = (idx >> 6) & 255, bh = idx >> 14;
  const float* zr = z + ((size_t)bh * NLM + i) * NLM;
  const float* Wb = W + (size_t)bh * NLM * DHEAD + d;
  float acc = 0.f;
  for (int j = 0; j < NLM; ++j) acc += zr[j] * Wb[(size_t)j * DHEAD];
  Ub[idx] = f2bf(acc);
}

// ------- MFMA flash attn1: gload_lds split pitch-32 staging, swapped PV epilogue -------
__global__ __launch_bounds__(256) void attn1_mfma(const bf16_t* __restrict__ q,
    const bf16_t* __restrict__ klb, const bf16_t* __restrict__ Ut,
    bf16_t* __restrict__ outp) {
  __shared__ __align__(16) bf16_t Qs0[2048], Qs1[2048];
  __shared__ __align__(16) bf16_t Ks0[2048], Ks1[2048];
  __shared__ __align__(16) bf16_t Vs0[2048], Vs1[2048];
  __shared__ __align__(16) bf16_t Ps[64][72];
  int nt = blockIdx.x, bh = blockIdx.y;
  int tid = threadIdx.x;
  int wave = tid >> 6, lane = tid & 63;
  int w = wave, tx = lane & 15, g = lane >> 4;
  int n0 = nt * 64;
  int b = bh >> 3, h = bh & 7;
  const bf16_t* klbb = klb + (size_t)bh * NLM * DHEAD;
  const bf16_t* utb = Ut + (size_t)bh * DHEAD * NLM;
  int eb = wave * 512;
  int e = eb + lane * 8;
  int sr = e >> 5, sc = e & 31;
  {
    const bf16_t* qrow = q + ((size_t)bh * NSEQ + n0 + sr) * DHEAD;
    gload16(qrow + sc, &Qs0[eb]);
    gload16(qrow + 32 + sc, &Qs1[eb]);
  }
  f32x4 oacc[4] = {};
  float lreg[4] = {0.f, 0.f, 0.f, 0.f};
  __syncthreads();
  bf16x8 aq0 = *reinterpret_cast<const bf16x8*>(&Qs0[(w * 16 + tx) * 32 + g * 8]);
  bf16x8 aq1 = *reinterpret_cast<const bf16x8*>(&Qs1[(w * 16 + tx) * 32 + g * 8]);
  for (int it = 0; it < 4; ++it) {
    int lm0 = it * 64;
    {
      const bf16_t* krow = klbb + (size_t)(lm0 + sr) * DHEAD;
      gload16(krow + sc, &Ks0[eb]);
      gload16(krow + 32 + sc, &Ks1[eb]);
      const bf16_t* urow = utb + (size_t)sr * NLM + lm0;
      gload16(urow + sc, &Vs0[eb]);
      gload16(urow + 32 + sc, &Vs1[eb]);
    }
    __syncthreads();
    f32x4 sacc[4] = {};
    #pragma unroll
    for (int tn = 0; tn < 4; ++tn) {
      bf16x8 bk0 = *reinterpret_cast<const bf16x8*>(&Ks0[(tn * 16 + tx) * 32 + g * 8]);
      bf16x8 bk1 = *reinterpret_cast<const bf16x8*>(&Ks1[(tn * 16 + tx) * 32 + g * 8]);
      sacc[tn] = __builtin_amdgcn_mfma_f32_16x16x32_bf16(aq0, bk0, sacc[tn], 0, 0, 0);
      sacc[tn] = __builtin_amdgcn_mfma_f32_16x16x32_bf16(aq1, bk1, sacc[tn], 0, 0, 0);
    }
    #pragma unroll
    for (int r = 0; r < 4; ++r) {
      float p0 = __expf(sacc[0][r]);
      float p1 = __expf(sacc[1][r]);
      float p2 = __expf(sacc[2][r]);
      float p3 = __expf(sacc[3][r]);
      float ts = p0 + p1 + p2 + p3;
      #pragma unroll
      for (int off = 1; off < 16; off <<= 1) ts += __shfl_xor(ts, off);
      lreg[r] += ts;
      int prow = w * 16 + g * 4 + r;
      Ps[prow][tx]      = f2bf(p0);
      Ps[prow][tx + 16] = f2bf(p1);
      Ps[prow][tx + 32] = f2bf(p2);
      Ps[prow][tx + 48] = f2bf(p3);
    }
    __syncthreads();
    bf16x8 ap0 = *reinterpret_cast<const bf16x8*>(&Ps[w * 16 + tx][g * 8]);
    bf16x8 ap1 = *reinterpret_cast<const bf16x8*>(&Ps[w * 16 + tx][g * 8 + 32]);
    #pragma unroll
    for (int td = 0; td < 4; ++td) {
      bf16x8 bv0 = *reinterpret_cast<const bf16x8*>(&Vs0[(td * 16 + tx) * 32 + g * 8]);
      bf16x8 bv1 = *reinterpret_cast<const bf16x8*>(&Vs1[(td * 16 + tx) * 32 + g * 8]);
      oacc[td] = __builtin_amdgcn_mfma_f32_16x16x32_bf16(bv0, ap0, oacc[td], 0, 0, 0);
      oacc[td] = __builtin_amdgcn_mfma_f32_16x16x32_bf16(bv1, ap1, oacc[td], 0, 0, 0);
    }
    __syncthreads();
  }
  float sel = lreg[0];
  sel = ((tx & 3) == 1) ? lreg[1] : sel;
  sel = ((tx & 3) == 2) ? lreg[2] : sel;
  sel = ((tx & 3) == 3) ? lreg[3] : sel;
  float inv = 1.0f / __shfl(sel, ((tx >> 2) << 4) | (tx & 3));
  int n = n0 + w * 16 + tx;
  #pragma unroll
  for (int td = 0; td < 4; ++td) {
    ushort4 o;
    o.x = f2bf(oacc[td][0] * inv);
    o.y = f2bf(oacc[td][1] * inv);
    o.z = f2bf(oacc[td][2] * inv);
    o.w = f2bf(oacc[td][3] * inv);
    *reinterpret_cast<ushort4*>(
        &outp[((size_t)(b * NSEQ + n)) * DMODEL + h * DHEAD + td * 16 + g * 4]) = o;
  }
}

// ---- depthwise conv residual, vT layout: lane=d (coalesced RMW), reg window ----
__global__ __launch_bounds__(256) void conv_kernel(const bf16_t* __restrict__ vT,
    const float* __restrict__ rk, bf16_t* __restrict__ outp) {
  int tile = blockIdx.x, bh = blockIdx.y;
  int b = bh >> 3, h = bh & 7;
  int tid = threadIdx.x;
  int w = tid >> 6, d = tid & 63;
  const bf16_t* vrow = vT + ((size_t)bh * DHEAD + d) * NSEQ;
  const float* wk = rk + h * KCONV;   // h block-uniform -> scalar loads
  int nbase = tile * 256 + w * 64;
  for (int i = 0; i < 8; ++i) {
    int ns = nbase + i * 8;
    int lo = ns - 16;
    __attribute__((aligned(16))) unsigned wv[20];  // 40 bf16 window, static-indexed
    if (lo >= 0 && ns + 24 <= NSEQ) {
      #pragma unroll
      for (int u = 0; u < 5; ++u)
        *reinterpret_cast<uint4*>(&wv[u * 4]) =
            *reinterpret_cast<const uint4*>(vrow + lo + u * 8);
    } else {
      #pragma unroll
      for (int u = 0; u < 20; ++u) {
        int n0e = lo + u * 2, n1e = n0e + 1;
        unsigned l16 = (n0e >= 0 && n0e < NSEQ) ? (unsigned)vrow[n0e] : 0u;
        unsigned h16 = (n1e >= 0 && n1e < NSEQ) ? (unsigned)vrow[n1e] : 0u;
        wv[u] = l16 | (h16 << 16);
      }
    }
    #pragma unroll
    for (int j = 0; j < 8; ++j) {
      float acc = 0.f;
      #pragma unroll
      for (int t = 0; t < KCONV; ++t) {
        int ix = j + t;
        unsigned word = wv[ix >> 1];
        float xv = __uint_as_float((ix & 1) ? (word & 0xffff0000u) : (word << 16));
        acc += wk[t] * xv;
      }
      int n = ns + j;
      size_t ob = ((size_t)(b * NSEQ + n)) * DMODEL + h * DHEAD + d;
      outp[ob] = f2bf(bf2f(outp[ob]) + acc);
    }
  }
}

extern "C" void kernel_launch(void* const* d_in, const int* in_sizes, int n_in,
                              void* d_out, int out_size, void* d_ws, size_t ws_size,
                              hipStream_t stream) {
  const float* x     = (const float*)d_in[0];
  const float* gamma = (const float*)d_in[1];
  const float* beta  = (const float*)d_in[2];
  const float* wqkv  = (const float*)d_in[3];
  const float* wout  = (const float*)d_in[4];
  const float* bout  = (const float*)d_in[5];
  const float* rk    = (const float*)d_in[6];
  float* y = (float*)d_out;

  // ---- workspace layout (round-22 proven addresses) ----
  char* wsb = (char*)d_ws;
  bf16_t* xn = (bf16_t*)(wsb);                   // 32 MB: LN out, then vT
  bf16_t* q  = (bf16_t*)(wsb + 33554432ull);     // 32 MB
  bf16_t* k  = (bf16_t*)(wsb + 67108864ull);     // 32 MB
  bf16_t* v  = (bf16_t*)(wsb + 100663296ull);    // 32 MB (dead after transpose)
  float* a2f = (float*)(wsb + 134217728ull);     // 8 MB fp32 a2 (dead after zinit)
  bf16_t* M2b = (bf16_t*)(wsb + 134217728ull);   // 4 MB over dead a2f
  bf16_t* M3b = (bf16_t*)(wsb + 138412032ull);   // 4 MB over dead a2f
  bf16_t* a2b = (bf16_t*)(wsb + 150994944ull);   // 4 MB (dead after Y0)
  bf16_t* zA  = (bf16_t*)(wsb + 155189248ull);   // 4 MB
  bf16_t* zB  = (bf16_t*)(wsb + 159383552ull);   // 4 MB
  bf16_t* YA  = (bf16_t*)(wsb + 163577856ull);   // 4 MB
  bf16_t* YB  = (bf16_t*)(wsb + 167772160ull);   // 4 MB
  float* zf  = (float*)(wsb + 150994944ull);     // 8 MB final z over dead a2b+zA
  float* ql  = (float*)(wsb + 176160768ull);     // 2 MB
  float* kl  = (float*)(wsb + 178257920ull);     // 2 MB
  float* Wm  = (float*)(wsb + 180355072ull);     // 2 MB
  bf16_t* Ub = (bf16_t*)(wsb + 182452224ull);    // 1 MB (shares wqkvT slot)
  unsigned int* scal = (unsigned int*)(wsb + 184549376ull);  // 8 B
  bf16_t* wqkvT = (bf16_t*)(wsb + 182452224ull); // 1.5 MB, dead before zw writes Ub
  bf16_t* woutT = (bf16_t*)(wsb + 184549440ull); // 512 KB
  bf16_t* qlb = (bf16_t*)(wsb + 185073728ull);   // 1 MB
  bf16_t* klb = (bf16_t*)(wsb + 186122304ull);   // 1 MB
  bf16_t* Ut  = (bf16_t*)(wsb + 187170880ull);   // 1 MB

  bf16_t* vT = xn;                               // LN data dead after gemm_qkv; live until conv
  float* Wpart  = (float*)(wsb + 134217728ull);  // 16 MB (M2b/M3b + free, dead after pinv)
  float* mlpart = (float*)(wsb + 167772160ull);  // 256 KB over dead YB
  bf16_t* out_pre = (bf16_t*)(wsb + 134217728ull); // 32 MB (after zw)

  castT2_kernel<<<4096, 256, 0, stream>>>(wqkv, wout, wqkvT, woutT, scal);
  ln_kernel<<<8192, 256, 0, stream>>>(x, gamma, beta, xn);
  gemm_qkv_mfma<<<3072, 256, 0, stream>>>(xn, wqkvT, q, k, v);
  transpose64_kernel<<<dim3(128, 32), 256, 0, stream>>>(v, vT, NSEQ);
  pool_kernel<<<4096, 256, 0, stream>>>(q, k, ql, kl, qlb, klb);
  attn2_kernel<<<dim3(256, 32), 256, 0, stream>>>(ql, kl, a2f);
  colrow_kernel<<<32, 256, 0, stream>>>(a2f, scal);
  zinit_kernel<<<8192, 256, 0, stream>>>(a2f, scal, zA, a2b);

  // ---- pinv via tracked-Y NS: Y=a2*z; per iter M2,M3, dual (z',Y'); 19 launches ----
  matmul256_b2b<<<dim3(16, 32), 256, 0, stream>>>(YA, a2b, zA, 0.f, -1.f);  // Y0 = a2*z0
  bf16_t *zc = zA, *zn = zB, *Yc = YA, *Yn = YB;
  for (int it = 0; it < 5; ++it) {
    matmul256_b2b<<<dim3(16, 32), 256, 0, stream>>>(M2b, Yc, Yc, 7.f, 1.f);   // M2 = 7Y - Y^2
    matmul256_b2b<<<dim3(16, 32), 256, 0, stream>>>(M3b, Yc, M2b, 15.f, 1.f); // M3 = 15Y - Y*M2
    matmul256_b2b2<<<dim3(16, 32, 2), 256, 0, stream>>>(zn, zc, Yn, Yc, M3b, 13.f, 0.25f);
    bf16_t* t;
    t = zc; zc = zn; zn = t;
    t = Yc; Yc = Yn; Yn = t;
  }
  // final iteration: z only, fp32 out
  matmul256_b2b<<<dim3(16, 32), 256, 0, stream>>>(M2b, Yc, Yc, 7.f, 1.f);
  matmul256_b2b<<<dim3(16, 32), 256, 0, stream>>>(M3b, Yc, M2b, 15.f, 1.f);
  matmul256_b2f<<<dim3(16, 32), 256, 0, stream>>>(zf, zc, M3b, 13.f, 0.25f);

  attn3v_mfma<<<dim3(CH3, 4, 32), 256, 0, stream>>>(qlb, k, vT, Wpart, mlpart);
  attn3v_combine<<<2048, 256, 0, stream>>>(Wpart, mlpart, Wm);
  zw_kernel<<<2048, 256, 0, stream>>>(zf, Wm, Ub);
  transpose64_kernel<<<dim3(4, 32), 256, 0, stream>>>(Ub, Ut, NLM);
  attn1_mfma<<<dim3(128, 32), 256, 0, stream>>>(q, klb, Ut, out_pre);
  conv_kernel<<<dim3(32, 32), 256, 0, stream>>>(vT, rk, out_pre);
  gemm_out_mfma<<<dim3(256, 4), 256, 0, stream>>>(out_pre, woutT, bout, x, y);
}

// Round 26
// 599.925 us; speedup vs baseline: 1.0026x; 1.0026x over previous
//
#include <hip/hip_runtime.h>
#include <math.h>

#define NB 4
#define NSEQ 8192
#define DMODEL 512
#define NHEADS 8
#define DHEAD 64
#define NLM 256
#define LTOK 32
#define NBH 32
#define KCONV 33
#define CH3 8

typedef unsigned short bf16_t;
typedef __attribute__((ext_vector_type(8))) short bf16x8;
typedef __attribute__((ext_vector_type(4))) float f32x4;

__device__ __forceinline__ float bf2f(bf16_t u) {
  return __uint_as_float(((unsigned)u) << 16);
}
__device__ __forceinline__ bf16_t f2bf(float f) {
  unsigned u = __float_as_uint(f);
  return (bf16_t)((u + 0x7fffu + ((u >> 16) & 1u)) >> 16);  // RTNE
}
__device__ __forceinline__ void bfpair(unsigned u, float& lo, float& hi) {
  lo = __uint_as_float(u << 16);
  hi = __uint_as_float(u & 0xffff0000u);
}
// composed B element: 7*Y - P, from packed bf16 pair words
__device__ __forceinline__ bf16_t comb7(unsigned yw, unsigned pw, bool hi) {
  float yv = __uint_as_float(hi ? (yw & 0xffff0000u) : (yw << 16));
  float pv = __uint_as_float(hi ? (pw & 0xffff0000u) : (pw << 16));
  return f2bf(7.0f * yv - pv);
}
// async global->LDS, 16B per lane; lds dest = wave-uniform base + lane*16
__device__ __forceinline__ void gload16(const bf16_t* g, bf16_t* l) {
  __builtin_amdgcn_global_load_lds(
      (const __attribute__((address_space(1))) unsigned int*)g,
      (__attribute__((address_space(3))) unsigned int*)l, 16, 0, 0);
}

// ---------------- LayerNorm ----------------
__global__ __launch_bounds__(256) void ln_kernel(const float* __restrict__ x,
    const float* __restrict__ gamma, const float* __restrict__ beta,
    bf16_t* __restrict__ xn) {
  int row = blockIdx.x * 4 + (threadIdx.x >> 6);
  int lane = threadIdx.x & 63;
  const float4* xr = reinterpret_cast<const float4*>(x + (size_t)row * DMODEL);
  float4 a0 = xr[lane];
  float4 a1 = xr[lane + 64];
  float s  = a0.x + a0.y + a0.z + a0.w + a1.x + a1.y + a1.z + a1.w;
  float s2 = a0.x*a0.x + a0.y*a0.y + a0.z*a0.z + a0.w*a0.w
           + a1.x*a1.x + a1.y*a1.y + a1.z*a1.z + a1.w*a1.w;
  #pragma unroll
  for (int off = 32; off; off >>= 1) {
    s  += __shfl_down(s, off);
    s2 += __shfl_down(s2, off);
  }
  s = __shfl(s, 0); s2 = __shfl(s2, 0);
  float mu = s * (1.0f / DMODEL);
  float var = s2 * (1.0f / DMODEL) - mu * mu;
  float rs = rsqrtf(var + 1e-5f);
  const float4* g4 = reinterpret_cast<const float4*>(gamma);
  const float4* b4 = reinterpret_cast<const float4*>(beta);
  float4 g0 = g4[lane], g1 = g4[lane + 64];
  float4 bb0 = b4[lane], bb1 = b4[lane + 64];
  ushort4 o0, o1;
  o0.x = f2bf((a0.x - mu) * rs * g0.x + bb0.x);
  o0.y = f2bf((a0.y - mu) * rs * g0.y + bb0.y);
  o0.z = f2bf((a0.z - mu) * rs * g0.z + bb0.z);
  o0.w = f2bf((a0.w - mu) * rs * g0.w + bb0.w);
  o1.x = f2bf((a1.x - mu) * rs * g1.x + bb1.x);
  o1.y = f2bf((a1.y - mu) * rs * g1.y + bb1.y);
  o1.z = f2bf((a1.z - mu) * rs * g1.z + bb1.z);
  o1.w = f2bf((a1.w - mu) * rs * g1.w + bb1.w);
  ushort4* o = reinterpret_cast<ushort4*>(xn + (size_t)row * DMODEL);
  o[lane] = o0; o[lane + 64] = o1;
}

// -------- merged transpose-cast of both weights (q cols pre-scaled); scal[0]=1.0 --------
__global__ void castT2_kernel(const float* __restrict__ wqkv, const float* __restrict__ wout,
                              bf16_t* __restrict__ wqkvT, bf16_t* __restrict__ woutT,
                              unsigned int* __restrict__ scal) {
  int idx = blockIdx.x * 256 + threadIdx.x;  // 786432 + 262144
  if (idx == 0) scal[0] = 0x3f800000u;  // col = row-sum max of softmax rows == 1.0
  if (idx == 1) scal[1] = 0u;
  if (idx < 786432) {
    int k = idx & 511, c = idx >> 9;
    float v = wqkv[(size_t)k * 1536 + c];
    if (c < 512) v *= 0.125f;  // dh^-0.5 folded into q weights
    wqkvT[idx] = f2bf(v);
  } else {
    int i = idx - 786432;
    int k = i & 511, c = i >> 9;
    woutT[i] = f2bf(wout[(size_t)k * 512 + c]);
  }
}

// ---- MFMA QKV GEMM: gload_lds BK=64 split buffers; XCD-swizzled 1-D grid ----
__global__ __launch_bounds__(256) void gemm_qkv_mfma(const bf16_t* __restrict__ A,
    const bf16_t* __restrict__ Bt, bf16_t* __restrict__ q, bf16_t* __restrict__ k,
    bf16_t* __restrict__ v) {
  __shared__ __align__(16) bf16_t As0[128 * 32];
  __shared__ __align__(16) bf16_t As1[128 * 32];
  __shared__ __align__(16) bf16_t Bs0[128 * 32];
  __shared__ __align__(16) bf16_t Bs1[128 * 32];
  int bid = blockIdx.x;
  int xcd = bid & 7;
  int idx = bid >> 3;                 // 0..383
  int rowT = xcd * 32 + idx / 12;     // 0..255
  int colT = idx % 12;                // 0..11
  int rowB = rowT * 128, colB = colT * 128;
  int tid = threadIdx.x;
  int wave = tid >> 6, lane = tid & 63;
  int wr = (wave >> 1) * 64, wc = (wave & 1) * 64;
  int lrow = lane & 15, g = lane >> 4;
  f32x4 acc[4][4] = {};
  for (int k0 = 0; k0 < DMODEL; k0 += 64) {
    #pragma unroll
    for (int c = 0; c < 2; ++c) {
      int eb = wave * 1024 + c * 512;       // wave-uniform element base
      int e = eb + lane * 8;
      int r = e >> 5, cc = e & 31;
      gload16(A + (size_t)(rowB + r) * DMODEL + k0 + cc, &As0[eb]);
      gload16(A + (size_t)(rowB + r) * DMODEL + k0 + 32 + cc, &As1[eb]);
      gload16(Bt + (size_t)(colB + r) * DMODEL + k0 + cc, &Bs0[eb]);
      gload16(Bt + (size_t)(colB + r) * DMODEL + k0 + 32 + cc, &Bs1[eb]);
    }
    __syncthreads();
    #pragma unroll
    for (int ks = 0; ks < 2; ++ks) {
      const bf16_t* Ab2 = ks ? As1 : As0;
      const bf16_t* Bb2 = ks ? Bs1 : Bs0;
      bf16x8 af[4], bf[4];
      #pragma unroll
      for (int m = 0; m < 4; ++m)
        af[m] = *reinterpret_cast<const bf16x8*>(&Ab2[(wr + m * 16 + lrow) * 32 + g * 8]);
      #pragma unroll
      for (int n = 0; n < 4; ++n)
        bf[n] = *reinterpret_cast<const bf16x8*>(&Bb2[(wc + n * 16 + lrow) * 32 + g * 8]);
      #pragma unroll
      for (int m = 0; m < 4; ++m)
        #pragma unroll
        for (int n = 0; n < 4; ++n)
          acc[m][n] = __builtin_amdgcn_mfma_f32_16x16x32_bf16(af[m], bf[n], acc[m][n], 0, 0, 0);
    }
    __syncthreads();
  }
  #pragma unroll
  for (int m = 0; m < 4; ++m) {
    #pragma unroll
    for (int n = 0; n < 4; ++n) {
      int col = colB + wc + n * 16 + lrow;
      int which = col >> 9, hc = col & 511, h = hc >> 6, d = hc & 63;
      bf16_t* dst = (which == 0) ? q : (which == 1 ? k : v);
      #pragma unroll
      for (int r = 0; r < 4; ++r) {
        int row = rowB + wr + m * 16 + g * 4 + r;
        int b = row >> 13, nn = row & 8191;
        dst[((size_t)(b * NHEADS + h) * NSEQ + nn) * DHEAD + d] = f2bf(acc[m][n][r]);
      }
    }
  }
}

// ---------------- MFMA out GEMM: gload_lds staging, swapped float4 epilogue ----------------
__global__ __launch_bounds__(256) void gemm_out_mfma(const bf16_t* __restrict__ A,
    const bf16_t* __restrict__ Bt, const float* __restrict__ bo,
    const float* __restrict__ x, float* __restrict__ y) {
  __shared__ __align__(16) bf16_t As[128 * 32];
  __shared__ __align__(16) bf16_t Bs[128 * 32];
  int rowB = blockIdx.x * 128, colB = blockIdx.y * 128;
  int tid = threadIdx.x;
  int wave = tid >> 6, lane = tid & 63;
  int wr = (wave >> 1) * 64, wc = (wave & 1) * 64;
  int lrow = lane & 15, g = lane >> 4;
  f32x4 acc[4][4] = {};  // [n][m]
  for (int k0 = 0; k0 < DMODEL; k0 += 32) {
    #pragma unroll
    for (int c = 0; c < 2; ++c) {
      int eb = wave * 1024 + c * 512;
      int e = eb + lane * 8;
      int r = e >> 5, cc = e & 31;
      gload16(A + (size_t)(rowB + r) * DMODEL + k0 + cc, &As[eb]);
      gload16(Bt + (size_t)(colB + r) * DMODEL + k0 + cc, &Bs[eb]);
    }
    __syncthreads();
    bf16x8 af[4], bf[4];
    #pragma unroll
    for (int m = 0; m < 4; ++m)
      af[m] = *reinterpret_cast<const bf16x8*>(&As[(wr + m * 16 + lrow) * 32 + g * 8]);
    #pragma unroll
    for (int n = 0; n < 4; ++n)
      bf[n] = *reinterpret_cast<const bf16x8*>(&Bs[(wc + n * 16 + lrow) * 32 + g * 8]);
    #pragma unroll
    for (int n = 0; n < 4; ++n)
      #pragma unroll
      for (int m = 0; m < 4; ++m)
        acc[n][m] = __builtin_amdgcn_mfma_f32_16x16x32_bf16(bf[n], af[m], acc[n][m], 0, 0, 0);
    __syncthreads();
  }
  #pragma unroll
  for (int n = 0; n < 4; ++n) {
    int c0 = colB + wc + n * 16 + g * 4;
    float4 b4 = *reinterpret_cast<const float4*>(&bo[c0]);
    #pragma unroll
    for (int m = 0; m < 4; ++m) {
      int row = rowB + wr + m * 16 + lrow;
      size_t off = (size_t)row * DMODEL + c0;
      float4 xv = *reinterpret_cast<const float4*>(&x[off]);
      float4 o;
      o.x = xv.x + b4.x + acc[n][m][0];
      o.y = xv.y + b4.y + acc[n][m][1];
      o.z = xv.z + b4.z + acc[n][m][2];
      o.w = xv.w + b4.w + acc[n][m][3];
      *reinterpret_cast<float4*>(&y[off]) = o;
    }
  }
}

// -------- conflict-free 64x64 tiled transpose: src [bh][R][64] -> dst [bh][64][R] --------
__global__ __launch_bounds__(256) void transpose64_kernel(const bf16_t* __restrict__ src,
    bf16_t* __restrict__ dst, int R) {
  __shared__ __align__(16) bf16_t T[64 * 64];
  int r0 = blockIdx.x * 64, bh = blockIdx.y;
  int tid = threadIdx.x;
  int jj = tid >> 2, part = tid & 3;
  const uint4* sr = reinterpret_cast<const uint4*>(
      src + ((size_t)bh * R + r0 + jj) * 64 + part * 16);
  uint4 a0 = sr[0], a1 = sr[1];
  int xr = (jj >> 3) & 7;
  int pg0 = (part * 2) ^ xr, pg1 = (part * 2 + 1) ^ xr;
  *reinterpret_cast<uint4*>(&T[jj * 64 + pg0 * 8]) = a0;
  *reinterpret_cast<uint4*>(&T[jj * 64 + pg1 * 8]) = a1;
  __syncthreads();
  int d = tid >> 2;
  unsigned ow[8];
  #pragma unroll
  for (int ee = 0; ee < 8; ++ee) {
    int n1 = part * 16 + ee * 2, n2 = n1 + 1;
    unsigned lo = T[n1 * 64 + (((d >> 3) ^ ((n1 >> 3) & 7)) * 8) + (d & 7)];
    unsigned hi = T[n2 * 64 + (((d >> 3) ^ ((n2 >> 3) & 7)) * 8) + (d & 7)];
    ow[ee] = lo | (hi << 16);
  }
  uint4* ot = reinterpret_cast<uint4*>(dst + ((size_t)bh * 64 + d) * R + r0 + part * 16);
  ot[0] = make_uint4(ow[0], ow[1], ow[2], ow[3]);
  ot[1] = make_uint4(ow[4], ow[5], ow[6], ow[7]);
}

// ---------------- landmark pooling: fp32 (attn2) + bf16 (flash) ----------------
__global__ void pool_kernel(const bf16_t* __restrict__ q, const bf16_t* __restrict__ k,
                            float* __restrict__ ql, float* __restrict__ kl,
                            bf16_t* __restrict__ qlb, bf16_t* __restrict__ klb) {
  int idx = blockIdx.x * 256 + threadIdx.x;
  const int half = NBH * NLM * DHEAD;
  const bf16_t* src = (idx < half) ? q : k;
  float* dst = (idx < half) ? ql : kl;
  bf16_t* dstb = (idx < half) ? qlb : klb;
  int i = (idx < half) ? idx : idx - half;
  int d = i & 63, m = (i >> 6) & 255, bh = i >> 14;
  const bf16_t* p = src + ((size_t)bh * NSEQ + m * LTOK) * DHEAD + d;
  float sum = 0.f;
  #pragma unroll
  for (int t = 0; t < LTOK; ++t) sum += bf2f(p[(size_t)t * DHEAD]);
  float r = sum * (1.0f / LTOK);
  dst[i] = r;
  dstb[i] = f2bf(r);
}

// ---------------- attn2 = softmax(q_l @ k_l^T) fp32 ----------------
__global__ __launch_bounds__(256) void attn2_kernel(const float* __restrict__ ql,
    const float* __restrict__ kl, float* __restrict__ a2) {
  __shared__ float qs[64];
  __shared__ float red[256];
  int bh = blockIdx.y, i = blockIdx.x, t = threadIdx.x;
  if (t < 64) qs[t] = ql[((size_t)bh * NLM + i) * DHEAD + t];
  __syncthreads();
  const float* kr = kl + ((size_t)bh * NLM + t) * DHEAD;
  float s = 0.f;
  #pragma unroll
  for (int d = 0; d < 64; ++d) s += qs[d] * kr[d];
  red[t] = s; __syncthreads();
  for (int off = 128; off; off >>= 1) { if (t < off) red[t] = fmaxf(red[t], red[t + off]); __syncthreads(); }
  float mx = red[0]; __syncthreads();
  float p = expf(s - mx);
  red[t] = p; __syncthreads();
  for (int off = 128; off; off >>= 1) { if (t < off) red[t] += red[t + off]; __syncthreads(); }
  a2[((size_t)bh * NLM + i) * NLM + t] = p / red[0];
}

// column-sum max only (row-sums of softmax are exactly 1 -> scal[0] preset)
__global__ void colrow_kernel(const float* __restrict__ a2, unsigned int* __restrict__ scal) {
  int bh = blockIdx.x;
  int t = threadIdx.x;
  const float* Ab = a2 + (size_t)bh * NLM * NLM;
  float sum = 0.f;
  for (int i2 = 0; i2 < NLM; ++i2) sum += fabsf(Ab[(size_t)i2 * NLM + t]);
  __shared__ float red[256];
  red[t] = sum; __syncthreads();
  for (int off = 128; off; off >>= 1) { if (t < off) red[t] = fmaxf(red[t], red[t + off]); __syncthreads(); }
  if (t == 0) atomicMax(&scal[1], __float_as_uint(red[0]));
}

// z0 = a^T/(col*row) in bf16, plus a2 cast to bf16
__global__ void zinit_kernel(const float* __restrict__ a2, const unsigned int* __restrict__ scal,
                             bf16_t* __restrict__ zb, bf16_t* __restrict__ a2b) {
  int idx = blockIdx.x * 256 + threadIdx.x;
  float inv = 1.0f / (__uint_as_float(scal[0]) * __uint_as_float(scal[1]));
  int j = idx & 255, i = (idx >> 8) & 255, bh = idx >> 16;
  zb[idx] = f2bf(a2[((size_t)bh * NLM + j) * NLM + i] * inv);
  a2b[idx] = f2bf(a2[idx]);
}

// ---------------- batched 256x256 matmul, bf16 in / bf16 out (2-stage, swapped epilogue) ----------------
__global__ __launch_bounds__(256) void matmul256_b2b(bf16_t* __restrict__ C,
    const bf16_t* __restrict__ A, const bf16_t* __restrict__ Bm, float s, float alpha) {
  __shared__ __align__(16) bf16_t Ah[64][72];
  __shared__ __align__(16) bf16_t Bh[64][72];
  int bh = blockIdx.y;
  const bf16_t* Ab = A + (size_t)bh * NLM * NLM;
  const bf16_t* Bb = Bm + (size_t)bh * NLM * NLM;
  bf16_t* Cb = C + (size_t)bh * NLM * NLM;
  int rowB = (blockIdx.x >> 2) * 64, colB = (blockIdx.x & 3) * 64;
  int tid = threadIdx.x, w = tid >> 6, lane = tid & 63, tx = lane & 15, g = lane >> 4;
  int jj = tid >> 2, part = tid & 3;
  f32x4 acc[4] = {};
  for (int k0 = 0; k0 < NLM; k0 += 64) {
    {
      const uint4* ar = reinterpret_cast<const uint4*>(
          Ab + (size_t)(rowB + jj) * NLM + k0 + part * 16);
      *reinterpret_cast<uint4*>(&Ah[jj][part * 16]) = ar[0];
      *reinterpret_cast<uint4*>(&Ah[jj][part * 16 + 8]) = ar[1];
      const uint4* br = reinterpret_cast<const uint4*>(
          Bb + (size_t)(k0 + jj) * NLM + colB + part * 16);
      uint4 b0 = br[0], b1 = br[1];
      int d0 = part * 16;
      Bh[d0+ 0][jj] = (bf16_t)(b0.x & 0xffffu); Bh[d0+ 1][jj] = (bf16_t)(b0.x >> 16);
      Bh[d0+ 2][jj] = (bf16_t)(b0.y & 0xffffu); Bh[d0+ 3][jj] = (bf16_t)(b0.y >> 16);
      Bh[d0+ 4][jj] = (bf16_t)(b0.z & 0xffffu); Bh[d0+ 5][jj] = (bf16_t)(b0.z >> 16);
      Bh[d0+ 6][jj] = (bf16_t)(b0.w & 0xffffu); Bh[d0+ 7][jj] = (bf16_t)(b0.w >> 16);
      Bh[d0+ 8][jj] = (bf16_t)(b1.x & 0xffffu); Bh[d0+ 9][jj] = (bf16_t)(b1.x >> 16);
      Bh[d0+10][jj] = (bf16_t)(b1.y & 0xffffu); Bh[d0+11][jj] = (bf16_t)(b1.y >> 16);
      Bh[d0+12][jj] = (bf16_t)(b1.z & 0xffffu); Bh[d0+13][jj] = (bf16_t)(b1.z >> 16);
      Bh[d0+14][jj] = (bf16_t)(b1.w & 0xffffu); Bh[d0+15][jj] = (bf16_t)(b1.w >> 16);
    }
    __syncthreads();
    #pragma unroll
    for (int ks = 0; ks < 2; ++ks) {
      bf16x8 ah = *reinterpret_cast<const bf16x8*>(&Ah[w * 16 + tx][g * 8 + 32 * ks]);
      #pragma unroll
      for (int tn = 0; tn < 4; ++tn) {
        bf16x8 bhf = *reinterpret_cast<const bf16x8*>(&Bh[tn * 16 + tx][g * 8 + 32 * ks]);
        acc[tn] = __builtin_amdgcn_mfma_f32_16x16x32_bf16(bhf, ah, acc[tn], 0, 0, 0);
      }
    }
    __syncthreads();
  }
  int rr = rowB + w * 16 + tx;
  #pragma unroll
  for (int tn = 0; tn < 4; ++tn) {
    int c0 = colB + tn * 16 + g * 4;
    size_t off = (size_t)rr * NLM + c0;
    float a0 = 0.f, a1 = 0.f, a2v = 0.f, a3 = 0.f;
    if (s != 0.0f) {
      ushort4 av = *reinterpret_cast<const ushort4*>(&Ab[off]);
      a0 = bf2f(av.x); a1 = bf2f(av.y); a2v = bf2f(av.z); a3 = bf2f(av.w);
    }
    ushort4 o;
    o.x = f2bf(alpha * (s * a0 - acc[tn][0]));
    o.y = f2bf(alpha * (s * a1 - acc[tn][1]));
    o.z = f2bf(alpha * (s * a2v - acc[tn][2]));
    o.w = f2bf(alpha * (s * a3 - acc[tn][3]));
    *reinterpret_cast<ushort4*>(&Cb[off]) = o;
  }
}

// ---- dual-product variant: blockIdx.z selects (C0,A0) or (C1,A1), shared B ----
__global__ __launch_bounds__(256) void matmul256_b2b2(
    bf16_t* __restrict__ C0, const bf16_t* __restrict__ A0,
    bf16_t* __restrict__ C1, const bf16_t* __restrict__ A1,
    const bf16_t* __restrict__ Bm, float s, float alpha) {
  __shared__ __align__(16) bf16_t Ah[64][72];
  __shared__ __align__(16) bf16_t Bh[64][72];
  int bh = blockIdx.y;
  const bf16_t* A = (blockIdx.z == 0) ? A0 : A1;
  bf16_t* C = (blockIdx.z == 0) ? C0 : C1;
  const bf16_t* Ab = A + (size_t)bh * NLM * NLM;
  const bf16_t* Bb = Bm + (size_t)bh * NLM * NLM;
  bf16_t* Cb = C + (size_t)bh * NLM * NLM;
  int rowB = (blockIdx.x >> 2) * 64, colB = (blockIdx.x & 3) * 64;
  int tid = threadIdx.x, w = tid >> 6, lane = tid & 63, tx = lane & 15, g = lane >> 4;
  int jj = tid >> 2, part = tid & 3;
  f32x4 acc[4] = {};
  for (int k0 = 0; k0 < NLM; k0 += 64) {
    {
      const uint4* ar = reinterpret_cast<const uint4*>(
          Ab + (size_t)(rowB + jj) * NLM + k0 + part * 16);
      *reinterpret_cast<uint4*>(&Ah[jj][part * 16]) = ar[0];
      *reinterpret_cast<uint4*>(&Ah[jj][part * 16 + 8]) = ar[1];
      const uint4* br = reinterpret_cast<const uint4*>(
          Bb + (size_t)(k0 + jj) * NLM + colB + part * 16);
      uint4 b0 = br[0], b1 = br[1];
      int d0 = part * 16;
      Bh[d0+ 0][jj] = (bf16_t)(b0.x & 0xffffu); Bh[d0+ 1][jj] = (bf16_t)(b0.x >> 16);
      Bh[d0+ 2][jj] = (bf16_t)(b0.y & 0xffffu); Bh[d0+ 3][jj] = (bf16_t)(b0.y >> 16);
      Bh[d0+ 4][jj] = (bf16_t)(b0.z & 0xffffu); Bh[d0+ 5][jj] = (bf16_t)(b0.z >> 16);
      Bh[d0+ 6][jj] = (bf16_t)(b0.w & 0xffffu); Bh[d0+ 7][jj] = (bf16_t)(b0.w >> 16);
      Bh[d0+ 8][jj] = (bf16_t)(b1.x & 0xffffu); Bh[d0+ 9][jj] = (bf16_t)(b1.x >> 16);
      Bh[d0+10][jj] = (bf16_t)(b1.y & 0xffffu); Bh[d0+11][jj] = (bf16_t)(b1.y >> 16);
      Bh[d0+12][jj] = (bf16_t)(b1.z & 0xffffu); Bh[d0+13][jj] = (bf16_t)(b1.z >> 16);
      Bh[d0+14][jj] = (bf16_t)(b1.w & 0xffffu); Bh[d0+15][jj] = (bf16_t)(b1.w >> 16);
    }
    __syncthreads();
    #pragma unroll
    for (int ks = 0; ks < 2; ++ks) {
      bf16x8 ah = *reinterpret_cast<const bf16x8*>(&Ah[w * 16 + tx][g * 8 + 32 * ks]);
      #pragma unroll
      for (int tn = 0; tn < 4; ++tn) {
        bf16x8 bhf = *reinterpret_cast<const bf16x8*>(&Bh[tn * 16 + tx][g * 8 + 32 * ks]);
        acc[tn] = __builtin_amdgcn_mfma_f32_16x16x32_bf16(bhf, ah, acc[tn], 0, 0, 0);
      }
    }
    __syncthreads();
  }
  int rr = rowB + w * 16 + tx;
  #pragma unroll
  for (int tn = 0; tn < 4; ++tn) {
    int c0 = colB + tn * 16 + g * 4;
    size_t off = (size_t)rr * NLM + c0;
    float a0 = 0.f, a1 = 0.f, a2v = 0.f, a3 = 0.f;
    if (s != 0.0f) {
      ushort4 av = *reinterpret_cast<const ushort4*>(&Ab[off]);
      a0 = bf2f(av.x); a1 = bf2f(av.y); a2v = bf2f(av.z); a3 = bf2f(av.w);
    }
    ushort4 o;
    o.x = f2bf(alpha * (s * a0 - acc[tn][0]));
    o.y = f2bf(alpha * (s * a1 - acc[tn][1]));
    o.z = f2bf(alpha * (s * a2v - acc[tn][2]));
    o.w = f2bf(alpha * (s * a3 - acc[tn][3]));
    *reinterpret_cast<ushort4*>(&Cb[off]) = o;
  }
}

// ---- dual-product, composed B = 7Y - P, 3-term epilogue ----
// C{0,1} = 0.25*(13*E{0,1} - 15*A{0,1} + A{0,1} @ (7*Y - P))
__global__ __launch_bounds__(256) void matmul256_b2b2m3(
    bf16_t* __restrict__ C0, const bf16_t* __restrict__ A0, const bf16_t* __restrict__ E0,
    bf16_t* __restrict__ C1, const bf16_t* __restrict__ A1, const bf16_t* __restrict__ E1,
    const bf16_t* __restrict__ Ym, const bf16_t* __restrict__ Pm) {
  __shared__ __align__(16) bf16_t Ah[64][72];
  __shared__ __align__(16) bf16_t Bh[64][72];
  int bh = blockIdx.y;
  const bf16_t* A = (blockIdx.z == 0) ? A0 : A1;
  const bf16_t* E = (blockIdx.z == 0) ? E0 : E1;
  bf16_t* C = (blockIdx.z == 0) ? C0 : C1;
  const bf16_t* Ab = A + (size_t)bh * NLM * NLM;
  const bf16_t* Eb = E + (size_t)bh * NLM * NLM;
  const bf16_t* Yb = Ym + (size_t)bh * NLM * NLM;
  const bf16_t* Pb = Pm + (size_t)bh * NLM * NLM;
  bf16_t* Cb = C + (size_t)bh * NLM * NLM;
  int rowB = (blockIdx.x >> 2) * 64, colB = (blockIdx.x & 3) * 64;
  int tid = threadIdx.x, w = tid >> 6, lane = tid & 63, tx = lane & 15, g = lane >> 4;
  int jj = tid >> 2, part = tid & 3;
  f32x4 acc[4] = {};
  for (int k0 = 0; k0 < NLM; k0 += 64) {
    {
      const uint4* ar = reinterpret_cast<const uint4*>(
          Ab + (size_t)(rowB + jj) * NLM + k0 + part * 16);
      *reinterpret_cast<uint4*>(&Ah[jj][part * 16]) = ar[0];
      *reinterpret_cast<uint4*>(&Ah[jj][part * 16 + 8]) = ar[1];
      size_t boff = (size_t)(k0 + jj) * NLM + colB + part * 16;
      const uint4* yr = reinterpret_cast<const uint4*>(Yb + boff);
      const uint4* pr = reinterpret_cast<const uint4*>(Pb + boff);
      uint4 y0 = yr[0], y1 = yr[1];
      uint4 p0 = pr[0], p1 = pr[1];
      int d0 = part * 16;
      Bh[d0+ 0][jj] = comb7(y0.x, p0.x, false); Bh[d0+ 1][jj] = comb7(y0.x, p0.x, true);
      Bh[d0+ 2][jj] = comb7(y0.y, p0.y, false); Bh[d0+ 3][jj] = comb7(y0.y, p0.y, true);
      Bh[d0+ 4][jj] = comb7(y0.z, p0.z, false); Bh[d0+ 5][jj] = comb7(y0.z, p0.z, true);
      Bh[d0+ 6][jj] = comb7(y0.w, p0.w, false); Bh[d0+ 7][jj] = comb7(y0.w, p0.w, true);
      Bh[d0+ 8][jj] = comb7(y1.x, p1.x, false); Bh[d0+ 9][jj] = comb7(y1.x, p1.x, true);
      Bh[d0+10][jj] = comb7(y1.y, p1.y, false); Bh[d0+11][jj] = comb7(y1.y, p1.y, true);
      Bh[d0+12][jj] = comb7(y1.z, p1.z, false); Bh[d0+13][jj] = comb7(y1.z, p1.z, true);
      Bh[d0+14][jj] = comb7(y1.w, p1.w, false); Bh[d0+15][jj] = comb7(y1.w, p1.w, true);
    }
    __syncthreads();
    #pragma unroll
    for (int ks = 0; ks < 2; ++ks) {
      bf16x8 ah = *reinterpret_cast<const bf16x8*>(&Ah[w * 16 + tx][g * 8 + 32 * ks]);
      #pragma unroll
      for (int tn = 0; tn < 4; ++tn) {
        bf16x8 bhf = *reinterpret_cast<const bf16x8*>(&Bh[tn * 16 + tx][g * 8 + 32 * ks]);
        acc[tn] = __builtin_amdgcn_mfma_f32_16x16x32_bf16(bhf, ah, acc[tn], 0, 0, 0);
      }
    }
    __syncthreads();
  }
  int rr = rowB + w * 16 + tx;
  #pragma unroll
  for (int tn = 0; tn < 4; ++tn) {
    int c0 = colB + tn * 16 + g * 4;
    size_t off = (size_t)rr * NLM + c0;
    ushort4 av = *reinterpret_cast<const ushort4*>(&Ab[off]);
    ushort4 ev = *reinterpret_cast<const ushort4*>(&Eb[off]);
    ushort4 o;
    o.x = f2bf(0.25f * (13.f * bf2f(ev.x) - 15.f * bf2f(av.x) + acc[tn][0]));
    o.y = f2bf(0.25f * (13.f * bf2f(ev.y) - 15.f * bf2f(av.y) + acc[tn][1]));
    o.z = f2bf(0.25f * (13.f * bf2f(ev.z) - 15.f * bf2f(av.z) + acc[tn][2]));
    o.w = f2bf(0.25f * (13.f * bf2f(ev.w) - 15.f * bf2f(av.w) + acc[tn][3]));
    *reinterpret_cast<ushort4*>(&Cb[off]) = o;
  }
}

// ---- single product, composed B = 7Y - P, 3-term epilogue, fp32 out (final z) ----
// C = 0.25*(13*E - 15*A + A @ (7*Y - P))
__global__ __launch_bounds__(256) void matmul256_b2fm3(float* __restrict__ C,
    const bf16_t* __restrict__ A, const bf16_t* __restrict__ E,
    const bf16_t* __restrict__ Ym, const bf16_t* __restrict__ Pm) {
  __shared__ __align__(16) bf16_t Ah[64][72];
  __shared__ __align__(16) bf16_t Bh[64][72];
  int bh = blockIdx.y;
  const bf16_t* Ab = A + (size_t)bh * NLM * NLM;
  const bf16_t* Eb = E + (size_t)bh * NLM * NLM;
  const bf16_t* Yb = Ym + (size_t)bh * NLM * NLM;
  const bf16_t* Pb = Pm + (size_t)bh * NLM * NLM;
  float* Cb = C + (size_t)bh * NLM * NLM;
  int rowB = (blockIdx.x >> 2) * 64, colB = (blockIdx.x & 3) * 64;
  int tid = threadIdx.x, w = tid >> 6, lane = tid & 63, tx = lane & 15, g = lane >> 4;
  int jj = tid >> 2, part = tid & 3;
  f32x4 acc[4] = {};
  for (int k0 = 0; k0 < NLM; k0 += 64) {
    {
      const uint4* ar = reinterpret_cast<const uint4*>(
          Ab + (size_t)(rowB + jj) * NLM + k0 + part * 16);
      *reinterpret_cast<uint4*>(&Ah[jj][part * 16]) = ar[0];
      *reinterpret_cast<uint4*>(&Ah[jj][part * 16 + 8]) = ar[1];
      size_t boff = (size_t)(k0 + jj) * NLM + colB + part * 16;
      const uint4* yr = reinterpret_cast<const uint4*>(Yb + boff);
      const uint4* pr = reinterpret_cast<const uint4*>(Pb + boff);
      uint4 y0 = yr[0], y1 = yr[1];
      uint4 p0 = pr[0], p1 = pr[1];
      int d0 = part * 16;
      Bh[d0+ 0][jj] = comb7(y0.x, p0.x, false); Bh[d0+ 1][jj] = comb7(y0.x, p0.x, true);
      Bh[d0+ 2][jj] = comb7(y0.y, p0.y, false); Bh[d0+ 3][jj] = comb7(y0.y, p0.y, true);
      Bh[d0+ 4][jj] = comb7(y0.z, p0.z, false); Bh[d0+ 5][jj] = comb7(y0.z, p0.z, true);
      Bh[d0+ 6][jj] = comb7(y0.w, p0.w, false); Bh[d0+ 7][jj] = comb7(y0.w, p0.w, true);
      Bh[d0+ 8][jj] = comb7(y1.x, p1.x, false); Bh[d0+ 9][jj] = comb7(y1.x, p1.x, true);
      Bh[d0+10][jj] = comb7(y1.y, p1.y, false); Bh[d0+11][jj] = comb7(y1.y, p1.y, true);
      Bh[d0+12][jj] = comb7(y1.z, p1.z, false); Bh[d0+13][jj] = comb7(y1.z, p1.z, true);
      Bh[d0+14][jj] = comb7(y1.w, p1.w, false); Bh[d0+15][jj] = comb7(y1.w, p1.w, true);
    }
    __syncthreads();
    #pragma unroll
    for (int ks = 0; ks < 2; ++ks) {
      bf16x8 ah = *reinterpret_cast<const bf16x8*>(&Ah[w * 16 + tx][g * 8 + 32 * ks]);
      #pragma unroll
      for (int tn = 0; tn < 4; ++tn) {
        bf16x8 bhf = *reinterpret_cast<const bf16x8*>(&Bh[tn * 16 + tx][g * 8 + 32 * ks]);
        acc[tn] = __builtin_amdgcn_mfma_f32_16x16x32_bf16(bhf, ah, acc[tn], 0, 0, 0);
      }
    }
    __syncthreads();
  }
  int rr = rowB + w * 16 + tx;
  #pragma unroll
  for (int tn = 0; tn < 4; ++tn) {
    int c0 = colB + tn * 16 + g * 4;
    size_t off = (size_t)rr * NLM + c0;
    ushort4 av = *reinterpret_cast<const ushort4*>(&Ab[off]);
    ushort4 ev = *reinterpret_cast<const ushort4*>(&Eb[off]);
    float4 o;
    o.x = 0.25f * (13.f * bf2f(ev.x) - 15.f * bf2f(av.x) + acc[tn][0]);
    o.y = 0.25f * (13.f * bf2f(ev.y) - 15.f * bf2f(av.y) + acc[tn][1]);
    o.z = 0.25f * (13.f * bf2f(ev.z) - 15.f * bf2f(av.z) + acc[tn][2]);
    o.w = 0.25f * (13.f * bf2f(ev.w) - 15.f * bf2f(av.w) + acc[tn][3]);
    *reinterpret_cast<float4*>(&Cb[off]) = o;
  }
}

// ------- MFMA flash attn3@v: gload_lds split pitch-32 staging, swapped PV epilogue -------
__global__ __launch_bounds__(256) void attn3v_mfma(const bf16_t* __restrict__ qlb,
    const bf16_t* __restrict__ k, const bf16_t* __restrict__ vT,
    float* __restrict__ Wpart, float* __restrict__ mlpart) {
  __shared__ __align__(16) bf16_t Qs0[2048], Qs1[2048];
  __shared__ __align__(16) bf16_t Ks0[2048], Ks1[2048];
  __shared__ __align__(16) bf16_t Vs0[2048], Vs1[2048];
  __shared__ __align__(16) bf16_t Ps[64][72];
  int chunk = blockIdx.x, lmt = blockIdx.y, bh = blockIdx.z;
  int tid = threadIdx.x;
  int wave = tid >> 6, lane = tid & 63;
  int w = wave, tx = lane & 15, g = lane >> 4;
  int lm0 = lmt * 64;
  const bf16_t* kb = k + (size_t)bh * NSEQ * DHEAD;
  const bf16_t* vtb = vT + (size_t)bh * DHEAD * NSEQ;
  int eb = wave * 512;
  int e = eb + lane * 8;
  int sr = e >> 5, sc = e & 31;
  {
    const bf16_t* qrow = qlb + ((size_t)bh * NLM + lm0 + sr) * DHEAD;
    gload16(qrow + sc, &Qs0[eb]);
    gload16(qrow + 32 + sc, &Qs1[eb]);
  }
  f32x4 oacc[4] = {};
  float lreg[4] = {0.f, 0.f, 0.f, 0.f};
  __syncthreads();
  bf16x8 aq0 = *reinterpret_cast<const bf16x8*>(&Qs0[(w * 16 + tx) * 32 + g * 8]);
  bf16x8 aq1 = *reinterpret_cast<const bf16x8*>(&Qs1[(w * 16 + tx) * 32 + g * 8]);
  for (int it = 0; it < NSEQ / (CH3 * 64); ++it) {
    int n0 = chunk * (NSEQ / CH3) + it * 64;
    {
      const bf16_t* krow = kb + (size_t)(n0 + sr) * DHEAD;
      gload16(krow + sc, &Ks0[eb]);
      gload16(krow + 32 + sc, &Ks1[eb]);
      const bf16_t* vrow = vtb + (size_t)sr * NSEQ + n0;
      gload16(vrow + sc, &Vs0[eb]);
      gload16(vrow + 32 + sc, &Vs1[eb]);
    }
    __syncthreads();
    f32x4 sacc[4] = {};
    #pragma unroll
    for (int tn = 0; tn < 4; ++tn) {
      bf16x8 bk0 = *reinterpret_cast<const bf16x8*>(&Ks0[(tn * 16 + tx) * 32 + g * 8]);
      bf16x8 bk1 = *reinterpret_cast<const bf16x8*>(&Ks1[(tn * 16 + tx) * 32 + g * 8]);
      sacc[tn] = __builtin_amdgcn_mfma_f32_16x16x32_bf16(aq0, bk0, sacc[tn], 0, 0, 0);
      sacc[tn] = __builtin_amdgcn_mfma_f32_16x16x32_bf16(aq1, bk1, sacc[tn], 0, 0, 0);
    }
    #pragma unroll
    for (int r = 0; r < 4; ++r) {
      float p0 = __expf(sacc[0][r]);
      float p1 = __expf(sacc[1][r]);
      float p2 = __expf(sacc[2][r]);
      float p3 = __expf(sacc[3][r]);
      float ts = p0 + p1 + p2 + p3;
      #pragma unroll
      for (int off = 1; off < 16; off <<= 1) ts += __shfl_xor(ts, off);
      lreg[r] += ts;
      int prow = w * 16 + g * 4 + r;
      Ps[prow][tx]      = f2bf(p0);
      Ps[prow][tx + 16] = f2bf(p1);
      Ps[prow][tx + 32] = f2bf(p2);
      Ps[prow][tx + 48] = f2bf(p3);
    }
    __syncthreads();
    bf16x8 ap0 = *reinterpret_cast<const bf16x8*>(&Ps[w * 16 + tx][g * 8]);
    bf16x8 ap1 = *reinterpret_cast<const bf16x8*>(&Ps[w * 16 + tx][g * 8 + 32]);
    #pragma unroll
    for (int td = 0; td < 4; ++td) {
      bf16x8 bv0 = *reinterpret_cast<const bf16x8*>(&Vs0[(td * 16 + tx) * 32 + g * 8]);
      bf16x8 bv1 = *reinterpret_cast<const bf16x8*>(&Vs1[(td * 16 + tx) * 32 + g * 8]);
      oacc[td] = __builtin_amdgcn_mfma_f32_16x16x32_bf16(bv0, ap0, oacc[td], 0, 0, 0);
      oacc[td] = __builtin_amdgcn_mfma_f32_16x16x32_bf16(bv1, ap1, oacc[td], 0, 0, 0);
    }
    __syncthreads();
  }
  size_t ob = ((size_t)(chunk * NBH + bh) * NLM + lm0 + w * 16 + tx);
  #pragma unroll
  for (int td = 0; td < 4; ++td) {
    float4 w4 = make_float4(oacc[td][0], oacc[td][1], oacc[td][2], oacc[td][3]);
    *reinterpret_cast<float4*>(&Wpart[ob * DHEAD + td * 16 + g * 4]) = w4;
  }
  if (tx == 0) {
    #pragma unroll
    for (int r = 0; r < 4; ++r) {
      size_t obr = ((size_t)(chunk * NBH + bh) * NLM + lm0 + w * 16 + g * 4 + r);
      mlpart[obr] = lreg[r];
    }
  }
}

// combine CH3 chunks (no-max softmax: plain sums)
__global__ void attn3v_combine(const float* __restrict__ Wpart,
    const float* __restrict__ mlpart, float* __restrict__ Wm) {
  int idx = blockIdx.x * 256 + threadIdx.x;
  int d = idx & 63;
  int s0 = idx >> 6;
  const int CHS = NBH * NLM;
  float L = 0.f, wv = 0.f;
  #pragma unroll
  for (int c = 0; c < CH3; ++c) {
    L += mlpart[(size_t)c * CHS + s0];
    wv += Wpart[((size_t)c * CHS + s0) * DHEAD + d];
  }
  Wm[idx] = wv / L;
}

// ---------------- U = Z @ W, bf16 out ----------------
__global__ void zw_kernel(const float* __restrict__ z, const float* __restrict__ W,
                          bf16_t* __restrict__ Ub) {
  int idx = blockIdx.x * 256 + threadIdx.x;
  int d = idx & 63, i = (idx >> 6) & 255, bh = idx >> 14;
  const float* zr = z + ((size_t)bh * NLM + i) * NLM;
  const float* Wb = W + (size_t)bh * NLM * DHEAD + d;
  float acc = 0.f;
  for (int j = 0; j < NLM; ++j) acc += zr[j] * Wb[(size_t)j * DHEAD];
  Ub[idx] = f2bf(acc);
}

// ------- MFMA flash attn1: gload_lds split pitch-32 staging, swapped PV epilogue -------
__global__ __launch_bounds__(256) void attn1_mfma(const bf16_t* __restrict__ q,
    const bf16_t* __restrict__ klb, const bf16_t* __restrict__ Ut,
    bf16_t* __restrict__ outp) {
  __shared__ __align__(16) bf16_t Qs0[2048], Qs1[2048];
  __shared__ __align__(16) bf16_t Ks0[2048], Ks1[2048];
  __shared__ __align__(16) bf16_t Vs0[2048], Vs1[2048];
  __shared__ __align__(16) bf16_t Ps[64][72];
  int nt = blockIdx.x, bh = blockIdx.y;
  int tid = threadIdx.x;
  int wave = tid >> 6, lane = tid & 63;
  int w = wave, tx = lane & 15, g = lane >> 4;
  int n0 = nt * 64;
  int b = bh >> 3, h = bh & 7;
  const bf16_t* klbb = klb + (size_t)bh * NLM * DHEAD;
  const bf16_t* utb = Ut + (size_t)bh * DHEAD * NLM;
  int eb = wave * 512;
  int e = eb + lane * 8;
  int sr = e >> 5, sc = e & 31;
  {
    const bf16_t* qrow = q + ((size_t)bh * NSEQ + n0 + sr) * DHEAD;
    gload16(qrow + sc, &Qs0[eb]);
    gload16(qrow + 32 + sc, &Qs1[eb]);
  }
  f32x4 oacc[4] = {};
  float lreg[4] = {0.f, 0.f, 0.f, 0.f};
  __syncthreads();
  bf16x8 aq0 = *reinterpret_cast<const bf16x8*>(&Qs0[(w * 16 + tx) * 32 + g * 8]);
  bf16x8 aq1 = *reinterpret_cast<const bf16x8*>(&Qs1[(w * 16 + tx) * 32 + g * 8]);
  for (int it = 0; it < 4; ++it) {
    int lm0 = it * 64;
    {
      const bf16_t* krow = klbb + (size_t)(lm0 + sr) * DHEAD;
      gload16(krow + sc, &Ks0[eb]);
      gload16(krow + 32 + sc, &Ks1[eb]);
      const bf16_t* urow = utb + (size_t)sr * NLM + lm0;
      gload16(urow + sc, &Vs0[eb]);
      gload16(urow + 32 + sc, &Vs1[eb]);
    }
    __syncthreads();
    f32x4 sacc[4] = {};
    #pragma unroll
    for (int tn = 0; tn < 4; ++tn) {
      bf16x8 bk0 = *reinterpret_cast<const bf16x8*>(&Ks0[(tn * 16 + tx) * 32 + g * 8]);
      bf16x8 bk1 = *reinterpret_cast<const bf16x8*>(&Ks1[(tn * 16 + tx) * 32 + g * 8]);
      sacc[tn] = __builtin_amdgcn_mfma_f32_16x16x32_bf16(aq0, bk0, sacc[tn], 0, 0, 0);
      sacc[tn] = __builtin_amdgcn_mfma_f32_16x16x32_bf16(aq1, bk1, sacc[tn], 0, 0, 0);
    }
    #pragma unroll
    for (int r = 0; r < 4; ++r) {
      float p0 = __expf(sacc[0][r]);
      float p1 = __expf(sacc[1][r]);
      float p2 = __expf(sacc[2][r]);
      float p3 = __expf(sacc[3][r]);
      float ts = p0 + p1 + p2 + p3;
      #pragma unroll
      for (int off = 1; off < 16; off <<= 1) ts += __shfl_xor(ts, off);
      lreg[r] += ts;
      int prow = w * 16 + g * 4 + r;
      Ps[prow][tx]      = f2bf(p0);
      Ps[prow][tx + 16] = f2bf(p1);
      Ps[prow][tx + 32] = f2bf(p2);
      Ps[prow][tx + 48] = f2bf(p3);
    }
    __syncthreads();
    bf16x8 ap0 = *reinterpret_cast<const bf16x8*>(&Ps[w * 16 + tx][g * 8]);
    bf16x8 ap1 = *reinterpret_cast<const bf16x8*>(&Ps[w * 16 + tx][g * 8 + 32]);
    #pragma unroll
    for (int td = 0; td < 4; ++td) {
      bf16x8 bv0 = *reinterpret_cast<const bf16x8*>(&Vs0[(td * 16 + tx) * 32 + g * 8]);
      bf16x8 bv1 = *reinterpret_cast<const bf16x8*>(&Vs1[(td * 16 + tx) * 32 + g * 8]);
      oacc[td] = __builtin_amdgcn_mfma_f32_16x16x32_bf16(bv0, ap0, oacc[td], 0, 0, 0);
      oacc[td] = __builtin_amdgcn_mfma_f32_16x16x32_bf16(bv1, ap1, oacc[td], 0, 0, 0);
    }
    __syncthreads();
  }
  float sel = lreg[0];
  sel = ((tx & 3) == 1) ? lreg[1] : sel;
  sel = ((tx & 3) == 2) ? lreg[2] : sel;
  sel = ((tx & 3) == 3) ? lreg[3] : sel;
  float inv = 1.0f / __shfl(sel, ((tx >> 2) << 4) | (tx & 3));
  int n = n0 + w * 16 + tx;
  #pragma unroll
  for (int td = 0; td < 4; ++td) {
    ushort4 o;
    o.x = f2bf(oacc[td][0] * inv);
    o.y = f2bf(oacc[td][1] * inv);
    o.z = f2bf(oacc[td][2] * inv);
    o.w = f2bf(oacc[td][3] * inv);
    *reinterpret_cast<ushort4*>(
        &outp[((size_t)(b * NSEQ + n)) * DMODEL + h * DHEAD + td * 16 + g * 4]) = o;
  }
}

// ---- depthwise conv residual, vT layout: lane=d (coalesced RMW), reg window ----
__global__ __launch_bounds__(256) void conv_kernel(const bf16_t* __restrict__ vT,
    const float* __restrict__ rk, bf16_t* __restrict__ outp) {
  int tile = blockIdx.x, bh = blockIdx.y;
  int b = bh >> 3, h = bh & 7;
  int tid = threadIdx.x;
  int w = tid >> 6, d = tid & 63;
  const bf16_t* vrow = vT + ((size_t)bh * DHEAD + d) * NSEQ;
  const float* wk = rk + h * KCONV;   // h block-uniform -> scalar loads
  int nbase = tile * 256 + w * 64;
  for (int i = 0; i < 8; ++i) {
    int ns = nbase + i * 8;
    int lo = ns - 16;
    __attribute__((aligned(16))) unsigned wv[20];  // 40 bf16 window, static-indexed
    if (lo >= 0 && ns + 24 <= NSEQ) {
      #pragma unroll
      for (int u = 0; u < 5; ++u)
        *reinterpret_cast<uint4*>(&wv[u * 4]) =
            *reinterpret_cast<const uint4*>(vrow + lo + u * 8);
    } else {
      #pragma unroll
      for (int u = 0; u < 20; ++u) {
        int n0e = lo + u * 2, n1e = n0e + 1;
        unsigned l16 = (n0e >= 0 && n0e < NSEQ) ? (unsigned)vrow[n0e] : 0u;
        unsigned h16 = (n1e >= 0 && n1e < NSEQ) ? (unsigned)vrow[n1e] : 0u;
        wv[u] = l16 | (h16 << 16);
      }
    }
    #pragma unroll
    for (int j = 0; j < 8; ++j) {
      float acc = 0.f;
      #pragma unroll
      for (int t = 0; t < KCONV; ++t) {
        int ix = j + t;
        unsigned word = wv[ix >> 1];
        float xv = __uint_as_float((ix & 1) ? (word & 0xffff0000u) : (word << 16));
        acc += wk[t] * xv;
      }
      int n = ns + j;
      size_t ob = ((size_t)(b * NSEQ + n)) * DMODEL + h * DHEAD + d;
      outp[ob] = f2bf(bf2f(outp[ob]) + acc);
    }
  }
}

extern "C" void kernel_launch(void* const* d_in, const int* in_sizes, int n_in,
                              void* d_out, int out_size, void* d_ws, size_t ws_size,
                              hipStream_t stream) {
  const float* x     = (const float*)d_in[0];
  const float* gamma = (const float*)d_in[1];
  const float* beta  = (const float*)d_in[2];
  const float* wqkv  = (const float*)d_in[3];
  const float* wout  = (const float*)d_in[4];
  const float* bout  = (const float*)d_in[5];
  const float* rk    = (const float*)d_in[6];
  float* y = (float*)d_out;

  // ---- workspace layout (round-24 proven addresses) ----
  char* wsb = (char*)d_ws;
  bf16_t* xn = (bf16_t*)(wsb);                   // 32 MB: LN out, then vT
  bf16_t* q  = (bf16_t*)(wsb + 33554432ull);     // 32 MB
  bf16_t* k  = (bf16_t*)(wsb + 67108864ull);     // 32 MB
  bf16_t* v  = (bf16_t*)(wsb + 100663296ull);    // 32 MB (dead after transpose)
  float* a2f = (float*)(wsb + 134217728ull);     // 8 MB fp32 a2 (dead after zinit)
  bf16_t* Pb = (bf16_t*)(wsb + 134217728ull);    // 4 MB over dead a2f (P = Y*Y)
  bf16_t* Nb = (bf16_t*)(wsb + 138412032ull);    // 4 MB over dead a2f (N = z*Y)
  bf16_t* a2b = (bf16_t*)(wsb + 150994944ull);   // 4 MB (dead after Y0)
  bf16_t* zA  = (bf16_t*)(wsb + 155189248ull);   // 4 MB
  bf16_t* zB  = (bf16_t*)(wsb + 159383552ull);   // 4 MB
  bf16_t* YA  = (bf16_t*)(wsb + 163577856ull);   // 4 MB
  bf16_t* YB  = (bf16_t*)(wsb + 167772160ull);   // 4 MB
  float* zf  = (float*)(wsb + 150994944ull);     // 8 MB final z over dead a2b+zA
  float* ql  = (float*)(wsb + 176160768ull);     // 2 MB
  float* kl  = (float*)(wsb + 178257920ull);     // 2 MB
  float* Wm  = (float*)(wsb + 180355072ull);     // 2 MB
  bf16_t* Ub = (bf16_t*)(wsb + 182452224ull);    // 1 MB (shares wqkvT slot)
  unsigned int* scal = (unsigned int*)(wsb + 184549376ull);  // 8 B
  bf16_t* wqkvT = (bf16_t*)(wsb + 182452224ull); // 1.5 MB, dead before zw writes Ub
  bf16_t* woutT = (bf16_t*)(wsb + 184549440ull); // 512 KB
  bf16_t* qlb = (bf16_t*)(wsb + 185073728ull);   // 1 MB
  bf16_t* klb = (bf16_t*)(wsb + 186122304ull);   // 1 MB
  bf16_t* Ut  = (bf16_t*)(wsb + 187170880ull);   // 1 MB

  bf16_t* vT = xn;                               // LN data dead after gemm_qkv; live until conv
  float* Wpart  = (float*)(wsb + 134217728ull);  // 16 MB (P/N + free, dead after pinv)
  float* mlpart = (float*)(wsb + 167772160ull);  // 256 KB over dead YB
  bf16_t* out_pre = (bf16_t*)(wsb + 134217728ull); // 32 MB (after zw)

  castT2_kernel<<<4096, 256, 0, stream>>>(wqkv, wout, wqkvT, woutT, scal);
  ln_kernel<<<8192, 256, 0, stream>>>(x, gamma, beta, xn);
  gemm_qkv_mfma<<<3072, 256, 0, stream>>>(xn, wqkvT, q, k, v);
  transpose64_kernel<<<dim3(128, 32), 256, 0, stream>>>(v, vT, NSEQ);
  pool_kernel<<<4096, 256, 0, stream>>>(q, k, ql, kl, qlb, klb);
  attn2_kernel<<<dim3(256, 32), 256, 0, stream>>>(ql, kl, a2f);
  colrow_kernel<<<32, 256, 0, stream>>>(a2f, scal);
  zinit_kernel<<<8192, 256, 0, stream>>>(a2f, scal, zA, a2b);

  // ---- pinv: re-associated cubic NS, 2 launches/iter; 13 launches total ----
  // iter: {P,N} = {Y,z}@Y ; then Y' = 0.25(13Y - 15P + P@(7Y-P)),
  //                              z' = 0.25(13z - 15N + N@(7Y-P))
  matmul256_b2b<<<dim3(16, 32), 256, 0, stream>>>(YA, a2b, zA, 0.f, -1.f);  // Y0 = a2*z0
  bf16_t *zc = zA, *zn = zB, *Yc = YA, *Yn = YB;
  for (int it = 0; it < 5; ++it) {
    matmul256_b2b2<<<dim3(16, 32, 2), 256, 0, stream>>>(Pb, Yc, Nb, zc, Yc, 0.f, -1.f);
    matmul256_b2b2m3<<<dim3(16, 32, 2), 256, 0, stream>>>(Yn, Pb, Yc, zn, Nb, zc, Yc, Pb);
    bf16_t* t;
    t = zc; zc = zn; zn = t;
    t = Yc; Yc = Yn; Yn = t;
  }
  // final iteration: z only, fp32 out (zc==zB, Yc==YB here)
  matmul256_b2b2<<<dim3(16, 32, 2), 256, 0, stream>>>(Pb, Yc, Nb, zc, Yc, 0.f, -1.f);
  matmul256_b2fm3<<<dim3(16, 32), 256, 0, stream>>>(zf, Nb, zc, Yc, Pb);

  attn3v_mfma<<<dim3(CH3, 4, 32), 256, 0, stream>>>(qlb, k, vT, Wpart, mlpart);
  attn3v_combine<<<2048, 256, 0, stream>>>(Wpart, mlpart, Wm);
  zw_kernel<<<2048, 256, 0, stream>>>(zf, Wm, Ub);
  transpose64_kernel<<<dim3(4, 32), 256, 0, stream>>>(Ub, Ut, NLM);
  attn1_mfma<<<dim3(128, 32), 256, 0, stream>>>(q, klb, Ut, out_pre);
  conv_kernel<<<dim3(32, 32), 256, 0, stream>>>(vT, rk, out_pre);
  gemm_out_mfma<<<dim3(256, 4), 256, 0, stream>>>(out_pre, woutT, bout, x, y);
}